// Round 14
// baseline (610.443 us; speedup 1.0000x reference)
//
#include <hip/hip_runtime.h>
#include <hip/hip_bf16.h>

// CrystalHypergraphConv — MI355X implementation.
//
// z[e] = A[idx0[e]] + C[idx1[e]];  A = h@(W0+W2)+b [N,256] f32-packed;
// C = cf@W1 [NHE,256] fp8-e4m3-packed (lane l owns {2l,2l+1,128+2l,129+2l}).
//
// R13 -> R14: k_aggr's 4-deep prefetch bookkeeping (min/max + 8 conditional
// loads per 4 edges) cost more than it saved at 50k resident waves. Now:
// branch-free 1-deep prefetch (clamped index, always issued), LN2/LOG2E
// folded (track M = sig*log2(1+u); msg = LN2*M; e^{t*msg} = 2^{t*M}) -> 2
// fewer muls/edge. bn1fin folded into k_aggr preamble; bn2fin into k_h2pool.

#define EPS_BN 1e-5f
#define LOG2E 1.4426950408889634f
#define LN2   0.6931471805599453f

typedef __attribute__((ext_vector_type(8))) short bf16x8;
typedef __attribute__((ext_vector_type(4))) float f32x4;
typedef __attribute__((ext_vector_type(2))) float f32x2;

__device__ __forceinline__ float fexp2(float x) {
#if __has_builtin(__builtin_amdgcn_exp2f)
    return __builtin_amdgcn_exp2f(x);
#else
    return __expf(x * LN2);
#endif
}
__device__ __forceinline__ float flog2(float x) {
#if __has_builtin(__builtin_amdgcn_logf)
    return __builtin_amdgcn_logf(x);
#else
    return __logf(x) * LOG2E;
#endif
}
__device__ __forceinline__ float softplus_fast(float x) {
    return LN2 * flog2(1.f + fexp2(x * LOG2E));
}

__device__ __forceinline__ unsigned short f2bf(float f) {
    unsigned u = __float_as_uint(f);
    unsigned r = (u + 0x7fffu + ((u >> 16) & 1u)) >> 16;   // RNE
    return (unsigned short)r;
}

// ---- fp8 e4m3 encode/decode (OCP; HW path on gfx950) ----
#if __has_builtin(__builtin_amdgcn_cvt_pk_f32_fp8) && __has_builtin(__builtin_amdgcn_cvt_pk_fp8_f32)
#define HW_FP8 1
#else
#define HW_FP8 0
#endif

__device__ __forceinline__ unsigned char f2fp8(float f) {
#if HW_FP8
    int r = __builtin_amdgcn_cvt_pk_fp8_f32(f, f, 0, false);
    return (unsigned char)(r & 0xff);
#else
    unsigned u = __float_as_uint(f);
    unsigned s = (u >> 24) & 0x80u;
    float af = fabsf(f);
    if (!(af >= 0.015625f)) {
        int m = (int)rintf(af * 512.f);
        if (m > 7) m = 7;
        return (unsigned char)(s | (unsigned)m);
    }
    if (af > 448.f) return (unsigned char)(s | 0x7e);
    unsigned au = __float_as_uint(af);
    unsigned r = au + 0x7ffffu + ((au >> 20) & 1u);
    int e8 = (int)(r >> 23) - 120;
    unsigned m = (r >> 20) & 7u;
    if (e8 > 15 || (e8 == 15 && m == 7)) return (unsigned char)(s | 0x7e);
    return (unsigned char)(s | ((unsigned)e8 << 3) | m);
#endif
}

__device__ __forceinline__ void fp8quad(unsigned p, float& a, float& b, float& c, float& d) {
#if HW_FP8
    f32x2 lo = __builtin_amdgcn_cvt_pk_f32_fp8((int)p, false);
    f32x2 hi = __builtin_amdgcn_cvt_pk_f32_fp8((int)p, true);
    a = lo.x; b = lo.y; c = hi.x; d = hi.y;
#else
    auto dec = [](unsigned byte) -> float {
        unsigned s = (byte & 0x80u) << 24;
        unsigned em = byte & 0x7fu;
        float nrm = __uint_as_float(s | ((em << 20) + 0x3C000000u));
        float sub = __uint_as_float(s | 0x3F800000u) * (float)em * 0.001953125f;
        return (em >= 8) ? nrm : sub;
    };
    a = dec(p & 0xff); b = dec((p >> 8) & 0xff);
    c = dec((p >> 16) & 0xff); d = dec(p >> 24);
#endif
}

__device__ __forceinline__ int perm256(int j) {
    return (j < 128) ? ((j >> 1) * 4 + (j & 1)) : (((j - 128) >> 1) * 4 + 2 + (j & 1));
}

// ---------------- weight prep: frag-major bf16 B tables ----------------
__global__ __launch_bounds__(256) void k_prepw(const float* __restrict__ ew, const float* __restrict__ bw,
                                               const float* __restrict__ lw,
                                               unsigned short* __restrict__ embB, unsigned short* __restrict__ bembB,
                                               unsigned short* __restrict__ waB, unsigned short* __restrict__ wcB) {
    int i = blockIdx.x * 256 + threadIdx.x;          // 0..81919
    if (i >= 81920) return;
    unsigned short* dst;
    int f, NKC, CT, mode;
    if (i < 12288)      { dst = embB;  f = i;         NKC = 3; CT = 2; mode = 0; }
    else if (i < 20480) { dst = bembB; f = i - 12288; NKC = 2; CT = 2; mode = 1; }
    else if (i < 53248) { dst = waB;   f = i - 20480; NKC = 4; CT = 4; mode = 2; }
    else                { dst = wcB;   f = i - 53248; NKC = 4; CT = 4; mode = 3; }
    int j = f & 7, l = (f >> 3) & 63;
    int r2 = f >> 9;
    int c = r2 % CT;
    int r3 = r2 / CT;
    int kc = r3 % NKC, w = r3 / NKC;
    int k = kc * 32 + ((l >> 4) & 3) * 8 + j;
    int n = (w * CT + c) * 16 + (l & 15);
    float v;
    if (mode == 0)      v = (k < 92) ? ew[k * 128 + n] : 0.f;
    else if (mode == 1) v = (k < 40) ? bw[k * 128 + n] : 0.f;
    else if (mode == 2) v = lw[k * 256 + n] + lw[(k + 256) * 256 + n];
    else                v = lw[(k + 128) * 256 + n];
    dst[f] = f2bf(v);
}

// ---------------- fused 2-stage MFMA GEMM ----------------
template<int KIN, int NKC1, int OMODE2>
__global__ __launch_bounds__(256) void mfma_fused(
    const float* __restrict__ in, const unsigned short* __restrict__ B1, const float* __restrict__ bias1,
    const unsigned short* __restrict__ B2, const float* __restrict__ bias2,
    float* __restrict__ hout, void* __restrict__ out2, int M)
{
    const int r0 = blockIdx.x * 32;
    const int t = threadIdx.x;
    const int w = t >> 6;
    const int l = t & 63;
    const int m = l & 15, q = l >> 4;

    __shared__ __align__(16) unsigned short als[32 * NKC1 * 32];
    __shared__ __align__(16) unsigned short hls[32 * 136];

    const int KP = NKC1 * 32;
    for (int i = t; i < 32 * KP; i += 256) {
        int r = i / KP, k = i - r * KP;
        int gr = r0 + r;
        float v = (gr < M && k < KIN) ? in[(size_t)gr * KIN + k] : 0.f;
        int idx = (((r >> 4) * NKC1 + (k >> 5)) * 64 + ((k >> 3) & 3) * 16 + (r & 15)) * 8 + (k & 7);
        als[idx] = f2bf(v);
    }
    bf16x8 b1[NKC1][2];
    const bf16x8* B1f = (const bf16x8*)B1;
#pragma unroll
    for (int kc = 0; kc < NKC1; kc++)
#pragma unroll
        for (int c = 0; c < 2; c++)
            b1[kc][c] = B1f[((w * NKC1 + kc) * 2 + c) * 64 + l];
    __syncthreads();

    f32x4 acc1[2][2];
#pragma unroll
    for (int c = 0; c < 2; c++) { acc1[c][0] = (f32x4){0.f,0.f,0.f,0.f}; acc1[c][1] = (f32x4){0.f,0.f,0.f,0.f}; }
    const bf16x8* af = (const bf16x8*)als;
#pragma unroll
    for (int kc = 0; kc < NKC1; kc++) {
        bf16x8 a0 = af[kc * 64 + l];
        bf16x8 a1 = af[(NKC1 + kc) * 64 + l];
#pragma unroll
        for (int c = 0; c < 2; c++) {
            acc1[c][0] = __builtin_amdgcn_mfma_f32_16x16x32_bf16(a0, b1[kc][c], acc1[c][0], 0, 0, 0);
            acc1[c][1] = __builtin_amdgcn_mfma_f32_16x16x32_bf16(a1, b1[kc][c], acc1[c][1], 0, 0, 0);
        }
    }
#pragma unroll
    for (int c = 0; c < 2; c++) {
        int n1 = (w * 2 + c) * 16 + m;
        float bv = bias1[n1];
#pragma unroll
        for (int hh = 0; hh < 2; hh++) {
#pragma unroll
            for (int r = 0; r < 4; r++) {
                int row = hh * 16 + q * 4 + r;
                float val = acc1[c][hh][r] + bv;
                hls[row * 136 + n1] = f2bf(val);
                if (OMODE2 == 1 && r0 + row < M) hout[(size_t)(r0 + row) * 128 + n1] = val;
            }
        }
    }
    __syncthreads();

    bf16x8 b2[4][4];
    const bf16x8* B2f = (const bf16x8*)B2;
#pragma unroll
    for (int kc = 0; kc < 4; kc++)
#pragma unroll
        for (int c = 0; c < 4; c++)
            b2[kc][c] = B2f[((w * 4 + kc) * 4 + c) * 64 + l];

    f32x4 acc2[4][2];
#pragma unroll
    for (int c = 0; c < 4; c++) { acc2[c][0] = (f32x4){0.f,0.f,0.f,0.f}; acc2[c][1] = (f32x4){0.f,0.f,0.f,0.f}; }
#pragma unroll
    for (int kc = 0; kc < 4; kc++) {
        bf16x8 a0 = *(const bf16x8*)(hls + m * 136 + kc * 32 + q * 8);
        bf16x8 a1 = *(const bf16x8*)(hls + (m + 16) * 136 + kc * 32 + q * 8);
#pragma unroll
        for (int c = 0; c < 4; c++) {
            acc2[c][0] = __builtin_amdgcn_mfma_f32_16x16x32_bf16(a0, b2[kc][c], acc2[c][0], 0, 0, 0);
            acc2[c][1] = __builtin_amdgcn_mfma_f32_16x16x32_bf16(a1, b2[kc][c], acc2[c][1], 0, 0, 0);
        }
    }
#pragma unroll
    for (int c = 0; c < 4; c++) {
        int n = (w * 4 + c) * 16 + m;
        float bv = bias2 ? bias2[n] : 0.f;
        int pj = perm256(n);
#pragma unroll
        for (int hh = 0; hh < 2; hh++) {
#pragma unroll
            for (int r = 0; r < 4; r++) {
                int row = r0 + hh * 16 + q * 4 + r;
                if (row < M) {
                    float val = acc2[c][hh][r] + bv;
                    if (OMODE2 == 1) ((float*)out2)[(size_t)row * 256 + pj] = val;
                    else             ((unsigned char*)out2)[(size_t)row * 256 + pj] = f2fp8(val);
                }
            }
        }
    }
}

// ---------------- histograms ----------------
__global__ __launch_bounds__(256) void k_hist2(const int* __restrict__ idx0, const int* __restrict__ batch,
                                               int* __restrict__ hist, int* __restrict__ gcount, int E, int N) {
    int i = blockIdx.x * 256 + threadIdx.x;
    if (i < E) atomicAdd(&hist[idx0[i]], 1);
    if (i < N) atomicAdd(&gcount[batch[i]], 1);
}

// ---------------- single-block scan: hist -> rowptr (N+1), gcount -> gptr (129) ----------------
__global__ __launch_bounds__(1024) void k_scanall(const int* __restrict__ hist, int* __restrict__ rowptr,
                                                  const int* __restrict__ gcount, int* __restrict__ gptr, int N) {
    __shared__ int s[1024];
    const int t = threadIdx.x;
    const int PER = (N + 1023) >> 10;
    const int b0 = t * PER;
    const int b1 = min(b0 + PER, N);
    int sum = 0;
    for (int i = b0; i < b1; i++) sum += hist[i];
    s[t] = sum;
    __syncthreads();
    for (int ofs = 1; ofs < 1024; ofs <<= 1) {
        int v = (t >= ofs) ? s[t - ofs] : 0;
        __syncthreads();
        s[t] += v;
        __syncthreads();
    }
    int run = s[t] - sum;
    for (int i = b0; i < b1; i++) {
        run += hist[i];
        rowptr[i + 1] = run;
    }
    if (t == 0) rowptr[0] = 0;
    __syncthreads();
    int gv = (t < 128) ? gcount[t] : 0;
    s[t] = gv;
    __syncthreads();
    for (int ofs = 1; ofs < 128; ofs <<= 1) {
        int v = (t >= ofs && t < 128) ? s[t - ofs] : 0;
        __syncthreads();
        if (t < 128) s[t] += v;
        __syncthreads();
    }
    if (t < 128) gptr[t + 1] = s[t];
    if (t == 0) gptr[0] = 0;
}

// ---------------- merged scatter ----------------
__global__ __launch_bounds__(256) void k_scatter2(const int* __restrict__ idx0, const int* __restrict__ idx1,
                                                  const int* __restrict__ batch,
                                                  const int* __restrict__ rowptr, const int* __restrict__ gptr,
                                                  int* __restrict__ fill, int* __restrict__ gfill,
                                                  int* __restrict__ sidx1, int* __restrict__ snode,
                                                  int* __restrict__ gnodes, int E, int N) {
    int i = blockIdx.x * 256 + threadIdx.x;
    if (i < E) {
        int n = idx0[i];
        int pos = rowptr[n] + atomicAdd(&fill[n], 1);
        sidx1[pos] = idx1[i];
    }
    if (i < N) {
        int a = rowptr[i], b = rowptr[i + 1];
        for (int e = a; e < b; e++) snode[e] = i;
        int g = batch[i];
        int pos = gptr[g] + atomicAdd(&gfill[g], 1);
        gnodes[pos] = i;
    }
}

// ---------------- BN1 stats: run-amortized A, 8-wide batched fp8 gathers ----------------
__global__ __launch_bounds__(256) void k_stats(const float* __restrict__ Apk, const unsigned* __restrict__ Cp8,
                                               const int* __restrict__ snode, const int* __restrict__ sidx1,
                                               float* __restrict__ gsum, float* __restrict__ gsq,
                                               int E, int per_slot) {
    __shared__ float4 lsm4[256], lsq4[256];
    const int t = threadIdx.x;
    const int s = t >> 6, l = t & 63;
    const float4* A4 = (const float4*)Apk;
    const long base = (long)(blockIdx.x * 4 + s) * per_slot;
    const int e0 = (int)min((long)E, base);
    const int e1 = (int)min((long)E, base + per_slot);
    float4 sm = {0.f, 0.f, 0.f, 0.f}, s2 = {0.f, 0.f, 0.f, 0.f};
    float4 csr = {0.f, 0.f, 0.f, 0.f};
    float4 a = {0.f, 0.f, 0.f, 0.f};
    int cur_n = -1, runk = 0;

    auto flush = [&]() {
        if (runk) {
            float fk = (float)runk;
            sm.x += fmaf(fk, a.x, csr.x);
            sm.y += fmaf(fk, a.y, csr.y);
            sm.z += fmaf(fk, a.z, csr.z);
            sm.w += fmaf(fk, a.w, csr.w);
            float t0 = fmaf(fk, a.x, 2.f * csr.x); s2.x = fmaf(a.x, t0, s2.x);
            float t1 = fmaf(fk, a.y, 2.f * csr.y); s2.y = fmaf(a.y, t1, s2.y);
            float t2 = fmaf(fk, a.z, 2.f * csr.z); s2.z = fmaf(a.z, t2, s2.z);
            float t3 = fmaf(fk, a.w, 2.f * csr.w); s2.w = fmaf(a.w, t3, s2.w);
        }
    };
    auto proc = [&](int n, unsigned p) {
        if (n != cur_n) {
            flush();
            a = A4[(size_t)n * 64 + l];
            cur_n = n; runk = 0;
            csr.x = 0.f; csr.y = 0.f; csr.z = 0.f; csr.w = 0.f;
        }
        float c0, c1, c2, c3;
        fp8quad(p, c0, c1, c2, c3);
        csr.x += c0; csr.y += c1; csr.z += c2; csr.w += c3;
        s2.x = fmaf(c0, c0, s2.x);
        s2.y = fmaf(c1, c1, s2.y);
        s2.z = fmaf(c2, c2, s2.z);
        s2.w = fmaf(c3, c3, s2.w);
        runk++;
    };

    int e = e0;
    for (; e + 8 <= e1; e += 8) {
        int4 nn0 = *(const int4*)(snode + e);
        int4 nn1 = *(const int4*)(snode + e + 4);
        int4 mm0 = *(const int4*)(sidx1 + e);
        int4 mm1 = *(const int4*)(sidx1 + e + 4);
        unsigned p0 = Cp8[(size_t)mm0.x * 64 + l];
        unsigned p1 = Cp8[(size_t)mm0.y * 64 + l];
        unsigned p2 = Cp8[(size_t)mm0.z * 64 + l];
        unsigned p3 = Cp8[(size_t)mm0.w * 64 + l];
        unsigned p4 = Cp8[(size_t)mm1.x * 64 + l];
        unsigned p5 = Cp8[(size_t)mm1.y * 64 + l];
        unsigned p6 = Cp8[(size_t)mm1.z * 64 + l];
        unsigned p7 = Cp8[(size_t)mm1.w * 64 + l];
        proc(nn0.x, p0); proc(nn0.y, p1); proc(nn0.z, p2); proc(nn0.w, p3);
        proc(nn1.x, p4); proc(nn1.y, p5); proc(nn1.z, p6); proc(nn1.w, p7);
    }
    for (; e < e1; e++) proc(snode[e], Cp8[(size_t)sidx1[e] * 64 + l]);
    flush();

    lsm4[t] = sm;
    lsq4[t] = s2;
    __syncthreads();
    const float* fm = (const float*)lsm4;
    const float* fq = (const float*)lsq4;
    float vs = fm[t] + fm[256 + t] + fm[512 + t] + fm[768 + t];
    float vq = fq[t] + fq[256 + t] + fq[512 + t] + fq[768 + t];
    atomicAdd(&gsum[t], vs);
    atomicAdd(&gsq[t], vq);
}

// ---------------- fused BN1-finalize + msg + segment softmax (4 waves/block, 1 node/wave) ----------------
// branch-free 1-deep prefetch; M-folded transcendentals: msg = LN2*M, e^{t*msg} = 2^{t*M}.
__global__ __launch_bounds__(256) void k_aggr(const float* __restrict__ Apk, const unsigned* __restrict__ Cp8,
                                              const int* __restrict__ rowptr, const int* __restrict__ sidx1,
                                              const float* __restrict__ bn1_sum, const float* __restrict__ bn1_sq,
                                              const float* __restrict__ g1, const float* __restrict__ b1,
                                              const float* __restrict__ tptr, float* __restrict__ out,
                                              float invE, int N, int E) {
    const int n = blockIdx.x * 4 + (threadIdx.x >> 6);
    if (n >= N) return;
    const int l = threadIdx.x & 63;
    const float t = tptr[0];
    // BN1 finalize for this lane's packed channels {2l, 2l+1, 128+2l, 129+2l}
    const float4 sum4 = ((const float4*)bn1_sum)[l];
    const float4 sq4  = ((const float4*)bn1_sq)[l];
    const float2 gf = ((const float2*)g1)[l];            // g[2l], g[2l+1]
    const float2 gc = ((const float2*)(g1 + 128))[l];    // g[128+2l], g[129+2l]
    const float2 bf2 = ((const float2*)b1)[l];
    const float2 bc2 = ((const float2*)(b1 + 128))[l];
    auto mkss = [&](float sum, float sq, float gg, float bb, float& sc, float& sh) {
        float mu = sum * invE;
        float var = sq * invE - mu * mu;
        sc = gg * rsqrtf(var + EPS_BN);
        sh = fmaf(-mu, sc, bb);
    };
    float scx, shx, scy, shy, scz, shz, scw, shw;
    mkss(sum4.x, sq4.x, gf.x, bf2.x, scx, shx);
    mkss(sum4.y, sq4.y, gf.y, bf2.y, scy, shy);
    mkss(sum4.z, sq4.z, gc.x, bc2.x, scz, shz);
    mkss(sum4.w, sq4.w, gc.y, bc2.y, scw, shw);

    const float4 ap = ((const float4*)Apk)[(size_t)n * 64 + l];
    const float sfx = -scx * LOG2E, sfy = -scy * LOG2E;
    const float bfx = -fmaf(ap.x, scx, shx) * LOG2E;
    const float bfy = -fmaf(ap.y, scy, shy) * LOG2E;
    const float sczz = scz * LOG2E, scww = scw * LOG2E;
    const float bcz = fmaf(ap.z, scz, shz) * LOG2E;
    const float bcw = fmaf(ap.w, scw, shw) * LOG2E;

    const int e0 = rowptr[n], e1 = rowptr[n + 1];
    float den0 = 0.f, num0 = 0.f, den1 = 0.f, num1 = 0.f;
    if (e1 > e0) {
        unsigned p = Cp8[(size_t)sidx1[e0] * 64 + l];
        for (int e = e0; e < e1; e++) {
            int enx = min(e + 1, E - 1);                 // wave-uniform clamp; always safe
            unsigned pn = Cp8[(size_t)sidx1[enx] * 64 + l];
            float c0, c1, c2, c3;
            fp8quad(p, c0, c1, c2, c3);
            float ef0 = fexp2(fmaf(c0, sfx, bfx));       // e^{-zf0} (base-2 domain)
            float ef1 = fexp2(fmaf(c1, sfy, bfy));
            float u0  = fexp2(fmaf(c2, sczz, bcz));      // 2^{zc0*log2e}
            float u1  = fexp2(fmaf(c3, scww, bcw));
            float sig0 = __builtin_amdgcn_rcpf(1.f + ef0);
            float sig1 = __builtin_amdgcn_rcpf(1.f + ef1);
            float M0 = sig0 * flog2(1.f + u0);           // msg = LN2*M
            float M1 = sig1 * flog2(1.f + u1);
            float w0 = fexp2(t * M0);                    // e^{t*msg} = 2^{t*M}
            float w1 = fexp2(t * M1);
            den0 += w0; num0 = fmaf(M0, w0, num0);
            den1 += w1; num1 = fmaf(M1, w1, num1);
            p = pn;
        }
    }
    float2 o;
    o.x = (e1 > e0) ? LN2 * num0 / den0 : 0.f;
    o.y = (e1 > e0) ? LN2 * num1 / den1 : 0.f;
    ((float2*)out)[(size_t)n * 64 + l] = o;
}

// ---------------- BN2 stats ----------------
__global__ __launch_bounds__(128) void k_bn2stats(const float* __restrict__ out, float* __restrict__ sum,
                                                  float* __restrict__ sq, int N) {
    const int c = threadIdx.x;
    const int n0 = blockIdx.x * 64;
    const int nend = min(n0 + 64, N);
    float sm = 0.f, s2 = 0.f;
    for (int n = n0; n < nend; n++) {
        float v = out[(size_t)n * 128 + c];
        sm += v;
        s2 = fmaf(v, v, s2);
    }
    atomicAdd(&sum[c], sm);
    atomicAdd(&sq[c], s2);
}

// ---------------- fused BN2-finalize + residual+softplus + mean-pool ----------------
template<int SPLIT>
__global__ __launch_bounds__(128) void k_h2pool(const float* __restrict__ out, const float* __restrict__ h,
                                                const int* __restrict__ gptr, const int* __restrict__ gnodes,
                                                const float* __restrict__ bn2_sum, const float* __restrict__ bn2_sq,
                                                const float* __restrict__ g2, const float* __restrict__ b2,
                                                float* __restrict__ pooled, float invN) {
    const int g = blockIdx.x & 127;
    const int sp = blockIdx.x >> 7;
    const int c = threadIdx.x;
    float mu = bn2_sum[c] * invN;
    float var = bn2_sq[c] * invN - mu * mu;
    float sc = g2[c] * rsqrtf(var + EPS_BN);
    float sh = fmaf(-mu, sc, b2[c]);
    const int i0 = gptr[g], i1 = gptr[g + 1];
    float acc = 0.f;
    for (int i = i0 + sp; i < i1; i += SPLIT) {
        int n = gnodes[i];
        float v = fmaf(out[(size_t)n * 128 + c], sc, sh) + h[(size_t)n * 128 + c];
        acc += softplus_fast(v);
    }
    if (acc != 0.f) atomicAdd(&pooled[g * 128 + c], acc);
}

// ---------------- head ----------------
__global__ __launch_bounds__(256) void k_head(const float* __restrict__ pooled, const int* __restrict__ gcount,
                                              const float* __restrict__ l1w, const float* __restrict__ l1b,
                                              const float* __restrict__ outw, const float* __restrict__ outb,
                                              float* __restrict__ dout) {
    __shared__ float p[128];
    __shared__ float red[256];
    const int g = blockIdx.x;
    const int j = threadIdx.x;
    if (j < 128) {
        float cnt = (float)max(gcount[g], 1);
        p[j] = pooled[g * 128 + j] / cnt;
    }
    __syncthreads();
    float acc = l1b[j];
    for (int k = 0; k < 128; k++) acc = fmaf(p[k], l1w[k * 256 + j], acc);
    red[j] = softplus_fast(acc) * outw[j];
    __syncthreads();
    for (int s = 128; s > 0; s >>= 1) {
        if (j < s) red[j] += red[j + s];
        __syncthreads();
    }
    if (j == 0) dout[g] = red[0] + outb[0];
}

// ---------------- launch ----------------
extern "C" void kernel_launch(void* const* d_in, const int* in_sizes, int n_in,
                              void* d_out, int out_size, void* d_ws, size_t ws_size,
                              hipStream_t stream) {
    const float* x        = (const float*)d_in[0];
    const float* hedge    = (const float*)d_in[1];
    const int*   iri      = (const int*)d_in[2];
    const int*   batch    = (const int*)d_in[3];
    const float* embed_w  = (const float*)d_in[5];
    const float* embed_b  = (const float*)d_in[6];
    const float* bembed_w = (const float*)d_in[7];
    const float* bembed_b = (const float*)d_in[8];
    const float* lin_w    = (const float*)d_in[9];
    const float* lin_b    = (const float*)d_in[10];
    const float* bn1_g    = (const float*)d_in[11];
    const float* bn1_b    = (const float*)d_in[12];
    const float* bn2_g    = (const float*)d_in[13];
    const float* bn2_b    = (const float*)d_in[14];
    const float* aggr_t   = (const float*)d_in[15];
    const float* l1_w     = (const float*)d_in[16];
    const float* l1_b     = (const float*)d_in[17];
    const float* out_w    = (const float*)d_in[18];
    const float* out_b    = (const float*)d_in[19];

    const int N   = in_sizes[0] / 92;
    const int NHE = in_sizes[1] / 40;
    const int E   = in_sizes[2] / 3;
    const int* idx0 = iri;
    const int* idx1 = iri + E;

    float* ws = (float*)d_ws;
    size_t off = 0;
    auto alloc = [&](size_t elems) -> float* {
        float* p = ws + off;
        off += (elems + 63) & ~(size_t)63;
        return p;
    };
    float* h      = alloc((size_t)N * 128);
    float* Apk    = alloc((size_t)N * 256);
    unsigned* Cp8 = (unsigned*)alloc((size_t)NHE * 64);
    unsigned short* embB  = (unsigned short*)alloc(6144);
    unsigned short* bembB = (unsigned short*)alloc(4096);
    unsigned short* waB   = (unsigned short*)alloc(16384);
    unsigned short* wcB   = (unsigned short*)alloc(16384);
    int*   rowptr = (int*)alloc((size_t)N + 1);
    int*   snode  = (int*)alloc((size_t)E + 8);
    int*   sidx1  = (int*)alloc((size_t)E + 8);
    int*   gptr   = (int*)alloc(129);
    int*   gnodes = (int*)alloc((size_t)N);
    float* outbuf = alloc((size_t)N * 128);
    // contiguous zero region
    float* zbase  = ws + off;
    int*   hist   = (int*)alloc((size_t)N);
    int*   fill   = (int*)alloc((size_t)N);
    int*   gfill  = (int*)alloc(128);
    float* bn1_sum = alloc(256);
    float* bn1_sq  = alloc(256);
    float* bn2_sum = alloc(128);
    float* bn2_sq  = alloc(128);
    float* pooled  = alloc(128 * 128);
    int*   gcount  = (int*)alloc(128);
    size_t zbytes = (size_t)((ws + off) - zbase) * sizeof(float);
    (void)ws_size;  // ~125MB; fit verified R1-R13

    hipMemsetAsync(zbase, 0, zbytes, stream);

    // frag-major bf16 weight prep + fused MFMA GEMM chains
    k_prepw<<<320, 256, 0, stream>>>(embed_w, bembed_w, lin_w, embB, bembB, waB, wcB);
    const int mtN   = (N + 31) / 32;
    const int mtNHE = (NHE + 31) / 32;
    mfma_fused<92, 3, 1><<<mtN, 256, 0, stream>>>(x, embB, embed_b, waB, lin_b, h, Apk, N);
    mfma_fused<40, 2, 2><<<mtNHE, 256, 0, stream>>>(hedge, bembB, bembed_b, wcB, nullptr, nullptr, Cp8, NHE);

    // CSR build
    k_hist2<<<(E + 255) / 256, 256, 0, stream>>>(idx0, batch, hist, gcount, E, N);
    k_scanall<<<1, 1024, 0, stream>>>(hist, rowptr, gcount, gptr, N);
    k_scatter2<<<(E + 255) / 256, 256, 0, stream>>>(idx0, idx1, batch, rowptr, gptr,
                                                    fill, gfill, sidx1, snode, gnodes, E, N);

    // BN1 stats
    const int STATS_BLOCKS = 2048;
    int per_slot = ((E + STATS_BLOCKS * 4 - 1) / (STATS_BLOCKS * 4) + 7) & ~7;
    k_stats<<<STATS_BLOCKS, 256, 0, stream>>>(Apk, Cp8, snode, sidx1, bn1_sum, bn1_sq, E, per_slot);

    // fused BN1-finalize + message + softmax aggregation
    k_aggr<<<(N + 3) / 4, 256, 0, stream>>>(Apk, Cp8, rowptr, sidx1, bn1_sum, bn1_sq,
                                            bn1_g, bn1_b, aggr_t, outbuf, 1.0f / (float)E, N, E);

    // BN2 stats + fused finalize/residual/softplus/pool
    k_bn2stats<<<(N + 63) / 64, 128, 0, stream>>>(outbuf, bn2_sum, bn2_sq, N);
    k_h2pool<16><<<128 * 16, 128, 0, stream>>>(outbuf, h, gptr, gnodes, bn2_sum, bn2_sq,
                                               bn2_g, bn2_b, pooled, 1.0f / (float)N);

    // head
    k_head<<<128, 256, 0, stream>>>(pooled, gcount, l1_w, l1_b, out_w, out_b, (float*)d_out);
}

// Round 15
// 599.278 us; speedup vs baseline: 1.0186x; 1.0186x over previous
//
#include <hip/hip_runtime.h>
#include <hip/hip_bf16.h>

// CrystalHypergraphConv — MI355X implementation.
//
// z[e] = A[idx0[e]] + C[idx1[e]];  A = h@(W0+W2)+b [N,256] f32-packed;
// C = cf@W1 [NHE,256] fp8-e4m3-packed (lane l owns {2l,2l+1,128+2l,129+2l}).
//
// R14 -> R15: R14's "simplified" 1-deep prefetch regressed k_aggr 83->101us
// (VALUBusy 75->65%): it cut outstanding gathers 4->1 and added a dependent
// sidx1 load per iteration. Restored the R13-proven 4-deep rolling prefetch
// verbatim; kept R14's wins (fused BN1/BN2 finalize, M-folded transcendentals).

#define EPS_BN 1e-5f
#define LOG2E 1.4426950408889634f
#define LN2   0.6931471805599453f

typedef __attribute__((ext_vector_type(8))) short bf16x8;
typedef __attribute__((ext_vector_type(4))) float f32x4;
typedef __attribute__((ext_vector_type(2))) float f32x2;

__device__ __forceinline__ float fexp2(float x) {
#if __has_builtin(__builtin_amdgcn_exp2f)
    return __builtin_amdgcn_exp2f(x);
#else
    return __expf(x * LN2);
#endif
}
__device__ __forceinline__ float flog2(float x) {
#if __has_builtin(__builtin_amdgcn_logf)
    return __builtin_amdgcn_logf(x);
#else
    return __logf(x) * LOG2E;
#endif
}
__device__ __forceinline__ float softplus_fast(float x) {
    return LN2 * flog2(1.f + fexp2(x * LOG2E));
}

__device__ __forceinline__ unsigned short f2bf(float f) {
    unsigned u = __float_as_uint(f);
    unsigned r = (u + 0x7fffu + ((u >> 16) & 1u)) >> 16;   // RNE
    return (unsigned short)r;
}

// ---- fp8 e4m3 encode/decode (OCP; HW path on gfx950) ----
#if __has_builtin(__builtin_amdgcn_cvt_pk_f32_fp8) && __has_builtin(__builtin_amdgcn_cvt_pk_fp8_f32)
#define HW_FP8 1
#else
#define HW_FP8 0
#endif

__device__ __forceinline__ unsigned char f2fp8(float f) {
#if HW_FP8
    int r = __builtin_amdgcn_cvt_pk_fp8_f32(f, f, 0, false);
    return (unsigned char)(r & 0xff);
#else
    unsigned u = __float_as_uint(f);
    unsigned s = (u >> 24) & 0x80u;
    float af = fabsf(f);
    if (!(af >= 0.015625f)) {
        int m = (int)rintf(af * 512.f);
        if (m > 7) m = 7;
        return (unsigned char)(s | (unsigned)m);
    }
    if (af > 448.f) return (unsigned char)(s | 0x7e);
    unsigned au = __float_as_uint(af);
    unsigned r = au + 0x7ffffu + ((au >> 20) & 1u);
    int e8 = (int)(r >> 23) - 120;
    unsigned m = (r >> 20) & 7u;
    if (e8 > 15 || (e8 == 15 && m == 7)) return (unsigned char)(s | 0x7e);
    return (unsigned char)(s | ((unsigned)e8 << 3) | m);
#endif
}

__device__ __forceinline__ void fp8quad(unsigned p, float& a, float& b, float& c, float& d) {
#if HW_FP8
    f32x2 lo = __builtin_amdgcn_cvt_pk_f32_fp8((int)p, false);
    f32x2 hi = __builtin_amdgcn_cvt_pk_f32_fp8((int)p, true);
    a = lo.x; b = lo.y; c = hi.x; d = hi.y;
#else
    auto dec = [](unsigned byte) -> float {
        unsigned s = (byte & 0x80u) << 24;
        unsigned em = byte & 0x7fu;
        float nrm = __uint_as_float(s | ((em << 20) + 0x3C000000u));
        float sub = __uint_as_float(s | 0x3F800000u) * (float)em * 0.001953125f;
        return (em >= 8) ? nrm : sub;
    };
    a = dec(p & 0xff); b = dec((p >> 8) & 0xff);
    c = dec((p >> 16) & 0xff); d = dec(p >> 24);
#endif
}

__device__ __forceinline__ int perm256(int j) {
    return (j < 128) ? ((j >> 1) * 4 + (j & 1)) : (((j - 128) >> 1) * 4 + 2 + (j & 1));
}

// ---------------- weight prep: frag-major bf16 B tables ----------------
__global__ __launch_bounds__(256) void k_prepw(const float* __restrict__ ew, const float* __restrict__ bw,
                                               const float* __restrict__ lw,
                                               unsigned short* __restrict__ embB, unsigned short* __restrict__ bembB,
                                               unsigned short* __restrict__ waB, unsigned short* __restrict__ wcB) {
    int i = blockIdx.x * 256 + threadIdx.x;          // 0..81919
    if (i >= 81920) return;
    unsigned short* dst;
    int f, NKC, CT, mode;
    if (i < 12288)      { dst = embB;  f = i;         NKC = 3; CT = 2; mode = 0; }
    else if (i < 20480) { dst = bembB; f = i - 12288; NKC = 2; CT = 2; mode = 1; }
    else if (i < 53248) { dst = waB;   f = i - 20480; NKC = 4; CT = 4; mode = 2; }
    else                { dst = wcB;   f = i - 53248; NKC = 4; CT = 4; mode = 3; }
    int j = f & 7, l = (f >> 3) & 63;
    int r2 = f >> 9;
    int c = r2 % CT;
    int r3 = r2 / CT;
    int kc = r3 % NKC, w = r3 / NKC;
    int k = kc * 32 + ((l >> 4) & 3) * 8 + j;
    int n = (w * CT + c) * 16 + (l & 15);
    float v;
    if (mode == 0)      v = (k < 92) ? ew[k * 128 + n] : 0.f;
    else if (mode == 1) v = (k < 40) ? bw[k * 128 + n] : 0.f;
    else if (mode == 2) v = lw[k * 256 + n] + lw[(k + 256) * 256 + n];
    else                v = lw[(k + 128) * 256 + n];
    dst[f] = f2bf(v);
}

// ---------------- fused 2-stage MFMA GEMM ----------------
template<int KIN, int NKC1, int OMODE2>
__global__ __launch_bounds__(256) void mfma_fused(
    const float* __restrict__ in, const unsigned short* __restrict__ B1, const float* __restrict__ bias1,
    const unsigned short* __restrict__ B2, const float* __restrict__ bias2,
    float* __restrict__ hout, void* __restrict__ out2, int M)
{
    const int r0 = blockIdx.x * 32;
    const int t = threadIdx.x;
    const int w = t >> 6;
    const int l = t & 63;
    const int m = l & 15, q = l >> 4;

    __shared__ __align__(16) unsigned short als[32 * NKC1 * 32];
    __shared__ __align__(16) unsigned short hls[32 * 136];

    const int KP = NKC1 * 32;
    for (int i = t; i < 32 * KP; i += 256) {
        int r = i / KP, k = i - r * KP;
        int gr = r0 + r;
        float v = (gr < M && k < KIN) ? in[(size_t)gr * KIN + k] : 0.f;
        int idx = (((r >> 4) * NKC1 + (k >> 5)) * 64 + ((k >> 3) & 3) * 16 + (r & 15)) * 8 + (k & 7);
        als[idx] = f2bf(v);
    }
    bf16x8 b1[NKC1][2];
    const bf16x8* B1f = (const bf16x8*)B1;
#pragma unroll
    for (int kc = 0; kc < NKC1; kc++)
#pragma unroll
        for (int c = 0; c < 2; c++)
            b1[kc][c] = B1f[((w * NKC1 + kc) * 2 + c) * 64 + l];
    __syncthreads();

    f32x4 acc1[2][2];
#pragma unroll
    for (int c = 0; c < 2; c++) { acc1[c][0] = (f32x4){0.f,0.f,0.f,0.f}; acc1[c][1] = (f32x4){0.f,0.f,0.f,0.f}; }
    const bf16x8* af = (const bf16x8*)als;
#pragma unroll
    for (int kc = 0; kc < NKC1; kc++) {
        bf16x8 a0 = af[kc * 64 + l];
        bf16x8 a1 = af[(NKC1 + kc) * 64 + l];
#pragma unroll
        for (int c = 0; c < 2; c++) {
            acc1[c][0] = __builtin_amdgcn_mfma_f32_16x16x32_bf16(a0, b1[kc][c], acc1[c][0], 0, 0, 0);
            acc1[c][1] = __builtin_amdgcn_mfma_f32_16x16x32_bf16(a1, b1[kc][c], acc1[c][1], 0, 0, 0);
        }
    }
#pragma unroll
    for (int c = 0; c < 2; c++) {
        int n1 = (w * 2 + c) * 16 + m;
        float bv = bias1[n1];
#pragma unroll
        for (int hh = 0; hh < 2; hh++) {
#pragma unroll
            for (int r = 0; r < 4; r++) {
                int row = hh * 16 + q * 4 + r;
                float val = acc1[c][hh][r] + bv;
                hls[row * 136 + n1] = f2bf(val);
                if (OMODE2 == 1 && r0 + row < M) hout[(size_t)(r0 + row) * 128 + n1] = val;
            }
        }
    }
    __syncthreads();

    bf16x8 b2[4][4];
    const bf16x8* B2f = (const bf16x8*)B2;
#pragma unroll
    for (int kc = 0; kc < 4; kc++)
#pragma unroll
        for (int c = 0; c < 4; c++)
            b2[kc][c] = B2f[((w * 4 + kc) * 4 + c) * 64 + l];

    f32x4 acc2[4][2];
#pragma unroll
    for (int c = 0; c < 4; c++) { acc2[c][0] = (f32x4){0.f,0.f,0.f,0.f}; acc2[c][1] = (f32x4){0.f,0.f,0.f,0.f}; }
#pragma unroll
    for (int kc = 0; kc < 4; kc++) {
        bf16x8 a0 = *(const bf16x8*)(hls + m * 136 + kc * 32 + q * 8);
        bf16x8 a1 = *(const bf16x8*)(hls + (m + 16) * 136 + kc * 32 + q * 8);
#pragma unroll
        for (int c = 0; c < 4; c++) {
            acc2[c][0] = __builtin_amdgcn_mfma_f32_16x16x32_bf16(a0, b2[kc][c], acc2[c][0], 0, 0, 0);
            acc2[c][1] = __builtin_amdgcn_mfma_f32_16x16x32_bf16(a1, b2[kc][c], acc2[c][1], 0, 0, 0);
        }
    }
#pragma unroll
    for (int c = 0; c < 4; c++) {
        int n = (w * 4 + c) * 16 + m;
        float bv = bias2 ? bias2[n] : 0.f;
        int pj = perm256(n);
#pragma unroll
        for (int hh = 0; hh < 2; hh++) {
#pragma unroll
            for (int r = 0; r < 4; r++) {
                int row = r0 + hh * 16 + q * 4 + r;
                if (row < M) {
                    float val = acc2[c][hh][r] + bv;
                    if (OMODE2 == 1) ((float*)out2)[(size_t)row * 256 + pj] = val;
                    else             ((unsigned char*)out2)[(size_t)row * 256 + pj] = f2fp8(val);
                }
            }
        }
    }
}

// ---------------- histograms ----------------
__global__ __launch_bounds__(256) void k_hist2(const int* __restrict__ idx0, const int* __restrict__ batch,
                                               int* __restrict__ hist, int* __restrict__ gcount, int E, int N) {
    int i = blockIdx.x * 256 + threadIdx.x;
    if (i < E) atomicAdd(&hist[idx0[i]], 1);
    if (i < N) atomicAdd(&gcount[batch[i]], 1);
}

// ---------------- single-block scan: hist -> rowptr (N+1), gcount -> gptr (129) ----------------
__global__ __launch_bounds__(1024) void k_scanall(const int* __restrict__ hist, int* __restrict__ rowptr,
                                                  const int* __restrict__ gcount, int* __restrict__ gptr, int N) {
    __shared__ int s[1024];
    const int t = threadIdx.x;
    const int PER = (N + 1023) >> 10;
    const int b0 = t * PER;
    const int b1 = min(b0 + PER, N);
    int sum = 0;
    for (int i = b0; i < b1; i++) sum += hist[i];
    s[t] = sum;
    __syncthreads();
    for (int ofs = 1; ofs < 1024; ofs <<= 1) {
        int v = (t >= ofs) ? s[t - ofs] : 0;
        __syncthreads();
        s[t] += v;
        __syncthreads();
    }
    int run = s[t] - sum;
    for (int i = b0; i < b1; i++) {
        run += hist[i];
        rowptr[i + 1] = run;
    }
    if (t == 0) rowptr[0] = 0;
    __syncthreads();
    int gv = (t < 128) ? gcount[t] : 0;
    s[t] = gv;
    __syncthreads();
    for (int ofs = 1; ofs < 128; ofs <<= 1) {
        int v = (t >= ofs && t < 128) ? s[t - ofs] : 0;
        __syncthreads();
        if (t < 128) s[t] += v;
        __syncthreads();
    }
    if (t < 128) gptr[t + 1] = s[t];
    if (t == 0) gptr[0] = 0;
}

// ---------------- merged scatter ----------------
__global__ __launch_bounds__(256) void k_scatter2(const int* __restrict__ idx0, const int* __restrict__ idx1,
                                                  const int* __restrict__ batch,
                                                  const int* __restrict__ rowptr, const int* __restrict__ gptr,
                                                  int* __restrict__ fill, int* __restrict__ gfill,
                                                  int* __restrict__ sidx1, int* __restrict__ snode,
                                                  int* __restrict__ gnodes, int E, int N) {
    int i = blockIdx.x * 256 + threadIdx.x;
    if (i < E) {
        int n = idx0[i];
        int pos = rowptr[n] + atomicAdd(&fill[n], 1);
        sidx1[pos] = idx1[i];
    }
    if (i < N) {
        int a = rowptr[i], b = rowptr[i + 1];
        for (int e = a; e < b; e++) snode[e] = i;
        int g = batch[i];
        int pos = gptr[g] + atomicAdd(&gfill[g], 1);
        gnodes[pos] = i;
    }
}

// ---------------- BN1 stats: run-amortized A, 8-wide batched fp8 gathers ----------------
__global__ __launch_bounds__(256) void k_stats(const float* __restrict__ Apk, const unsigned* __restrict__ Cp8,
                                               const int* __restrict__ snode, const int* __restrict__ sidx1,
                                               float* __restrict__ gsum, float* __restrict__ gsq,
                                               int E, int per_slot) {
    __shared__ float4 lsm4[256], lsq4[256];
    const int t = threadIdx.x;
    const int s = t >> 6, l = t & 63;
    const float4* A4 = (const float4*)Apk;
    const long base = (long)(blockIdx.x * 4 + s) * per_slot;
    const int e0 = (int)min((long)E, base);
    const int e1 = (int)min((long)E, base + per_slot);
    float4 sm = {0.f, 0.f, 0.f, 0.f}, s2 = {0.f, 0.f, 0.f, 0.f};
    float4 csr = {0.f, 0.f, 0.f, 0.f};
    float4 a = {0.f, 0.f, 0.f, 0.f};
    int cur_n = -1, runk = 0;

    auto flush = [&]() {
        if (runk) {
            float fk = (float)runk;
            sm.x += fmaf(fk, a.x, csr.x);
            sm.y += fmaf(fk, a.y, csr.y);
            sm.z += fmaf(fk, a.z, csr.z);
            sm.w += fmaf(fk, a.w, csr.w);
            float t0 = fmaf(fk, a.x, 2.f * csr.x); s2.x = fmaf(a.x, t0, s2.x);
            float t1 = fmaf(fk, a.y, 2.f * csr.y); s2.y = fmaf(a.y, t1, s2.y);
            float t2 = fmaf(fk, a.z, 2.f * csr.z); s2.z = fmaf(a.z, t2, s2.z);
            float t3 = fmaf(fk, a.w, 2.f * csr.w); s2.w = fmaf(a.w, t3, s2.w);
        }
    };
    auto proc = [&](int n, unsigned p) {
        if (n != cur_n) {
            flush();
            a = A4[(size_t)n * 64 + l];
            cur_n = n; runk = 0;
            csr.x = 0.f; csr.y = 0.f; csr.z = 0.f; csr.w = 0.f;
        }
        float c0, c1, c2, c3;
        fp8quad(p, c0, c1, c2, c3);
        csr.x += c0; csr.y += c1; csr.z += c2; csr.w += c3;
        s2.x = fmaf(c0, c0, s2.x);
        s2.y = fmaf(c1, c1, s2.y);
        s2.z = fmaf(c2, c2, s2.z);
        s2.w = fmaf(c3, c3, s2.w);
        runk++;
    };

    int e = e0;
    for (; e + 8 <= e1; e += 8) {
        int4 nn0 = *(const int4*)(snode + e);
        int4 nn1 = *(const int4*)(snode + e + 4);
        int4 mm0 = *(const int4*)(sidx1 + e);
        int4 mm1 = *(const int4*)(sidx1 + e + 4);
        unsigned p0 = Cp8[(size_t)mm0.x * 64 + l];
        unsigned p1 = Cp8[(size_t)mm0.y * 64 + l];
        unsigned p2 = Cp8[(size_t)mm0.z * 64 + l];
        unsigned p3 = Cp8[(size_t)mm0.w * 64 + l];
        unsigned p4 = Cp8[(size_t)mm1.x * 64 + l];
        unsigned p5 = Cp8[(size_t)mm1.y * 64 + l];
        unsigned p6 = Cp8[(size_t)mm1.z * 64 + l];
        unsigned p7 = Cp8[(size_t)mm1.w * 64 + l];
        proc(nn0.x, p0); proc(nn0.y, p1); proc(nn0.z, p2); proc(nn0.w, p3);
        proc(nn1.x, p4); proc(nn1.y, p5); proc(nn1.z, p6); proc(nn1.w, p7);
    }
    for (; e < e1; e++) proc(snode[e], Cp8[(size_t)sidx1[e] * 64 + l]);
    flush();

    lsm4[t] = sm;
    lsq4[t] = s2;
    __syncthreads();
    const float* fm = (const float*)lsm4;
    const float* fq = (const float*)lsq4;
    float vs = fm[t] + fm[256 + t] + fm[512 + t] + fm[768 + t];
    float vq = fq[t] + fq[256 + t] + fq[512 + t] + fq[768 + t];
    atomicAdd(&gsum[t], vs);
    atomicAdd(&gsq[t], vq);
}

// ---------------- fused BN1-finalize + msg + segment softmax (4 waves/block, 1 node/wave) ----------------
// R13-proven 4-deep rolling prefetch; M-folded transcendentals.
__global__ __launch_bounds__(256) void k_aggr(const float* __restrict__ Apk, const unsigned* __restrict__ Cp8,
                                              const int* __restrict__ rowptr, const int* __restrict__ sidx1,
                                              const float* __restrict__ bn1_sum, const float* __restrict__ bn1_sq,
                                              const float* __restrict__ g1, const float* __restrict__ b1,
                                              const float* __restrict__ tptr, float* __restrict__ out,
                                              float invE, int N) {
    const int n = blockIdx.x * 4 + (threadIdx.x >> 6);
    if (n >= N) return;
    const int l = threadIdx.x & 63;
    const float t = tptr[0];
    // BN1 finalize for this lane's packed channels {2l, 2l+1, 128+2l, 129+2l}
    const float4 sum4 = ((const float4*)bn1_sum)[l];
    const float4 sq4  = ((const float4*)bn1_sq)[l];
    const float2 gf = ((const float2*)g1)[l];
    const float2 gc = ((const float2*)(g1 + 128))[l];
    const float2 bf2 = ((const float2*)b1)[l];
    const float2 bc2 = ((const float2*)(b1 + 128))[l];
    auto mkss = [&](float sum, float sq, float gg, float bb, float& sc, float& sh) {
        float mu = sum * invE;
        float var = sq * invE - mu * mu;
        sc = gg * rsqrtf(var + EPS_BN);
        sh = fmaf(-mu, sc, bb);
    };
    float scx, shx, scy, shy, scz, shz, scw, shw;
    mkss(sum4.x, sq4.x, gf.x, bf2.x, scx, shx);
    mkss(sum4.y, sq4.y, gf.y, bf2.y, scy, shy);
    mkss(sum4.z, sq4.z, gc.x, bc2.x, scz, shz);
    mkss(sum4.w, sq4.w, gc.y, bc2.y, scw, shw);

    const float4 ap = ((const float4*)Apk)[(size_t)n * 64 + l];
    const float sfx = -scx * LOG2E, sfy = -scy * LOG2E;
    const float bfx = -fmaf(ap.x, scx, shx) * LOG2E;
    const float bfy = -fmaf(ap.y, scy, shy) * LOG2E;
    const float sczz = scz * LOG2E, scww = scw * LOG2E;
    const float bcz = fmaf(ap.z, scz, shz) * LOG2E;
    const float bcw = fmaf(ap.w, scw, shw) * LOG2E;

    const int e0 = rowptr[n], e1 = rowptr[n + 1];
    float den0 = 0.f, num0 = 0.f, den1 = 0.f, num1 = 0.f;

    auto proc = [&](unsigned p) {
        float c0, c1, c2, c3;
        fp8quad(p, c0, c1, c2, c3);
        float ef0 = fexp2(fmaf(c0, sfx, bfx));           // e^{-zf0}
        float ef1 = fexp2(fmaf(c1, sfy, bfy));
        float u0  = fexp2(fmaf(c2, sczz, bcz));          // 2^{zc0*log2e}
        float u1  = fexp2(fmaf(c3, scww, bcw));
        float sig0 = __builtin_amdgcn_rcpf(1.f + ef0);
        float sig1 = __builtin_amdgcn_rcpf(1.f + ef1);
        float M0 = sig0 * flog2(1.f + u0);               // msg = LN2*M
        float M1 = sig1 * flog2(1.f + u1);
        float w0 = fexp2(t * M0);                        // e^{t*msg} = 2^{t*M}
        float w1 = fexp2(t * M1);
        den0 += w0; num0 = fmaf(M0, w0, num0);
        den1 += w1; num1 = fmaf(M1, w1, num1);
    };

    if (e1 > e0) {
        unsigned cur[4];
        int cb = min(e1 - e0, 4);
#pragma unroll
        for (int i = 0; i < 4; i++)
            if (i < cb) cur[i] = Cp8[(size_t)sidx1[e0 + i] * 64 + l];
        for (int eb = e0; eb < e1; eb += 4) {
            int nb = min(max(e1 - (eb + 4), 0), 4);
            unsigned nxt[4];
#pragma unroll
            for (int i = 0; i < 4; i++)
                if (i < nb) nxt[i] = Cp8[(size_t)sidx1[eb + 4 + i] * 64 + l];
            int pb = min(e1 - eb, 4);
#pragma unroll
            for (int i = 0; i < 4; i++)
                if (i < pb) proc(cur[i]);
#pragma unroll
            for (int i = 0; i < 4; i++) cur[i] = nxt[i];
        }
    }
    float2 o;
    o.x = (e1 > e0) ? LN2 * num0 / den0 : 0.f;
    o.y = (e1 > e0) ? LN2 * num1 / den1 : 0.f;
    ((float2*)out)[(size_t)n * 64 + l] = o;
}

// ---------------- BN2 stats ----------------
__global__ __launch_bounds__(128) void k_bn2stats(const float* __restrict__ out, float* __restrict__ sum,
                                                  float* __restrict__ sq, int N) {
    const int c = threadIdx.x;
    const int n0 = blockIdx.x * 64;
    const int nend = min(n0 + 64, N);
    float sm = 0.f, s2 = 0.f;
    for (int n = n0; n < nend; n++) {
        float v = out[(size_t)n * 128 + c];
        sm += v;
        s2 = fmaf(v, v, s2);
    }
    atomicAdd(&sum[c], sm);
    atomicAdd(&sq[c], s2);
}

// ---------------- fused BN2-finalize + residual+softplus + mean-pool ----------------
template<int SPLIT>
__global__ __launch_bounds__(128) void k_h2pool(const float* __restrict__ out, const float* __restrict__ h,
                                                const int* __restrict__ gptr, const int* __restrict__ gnodes,
                                                const float* __restrict__ bn2_sum, const float* __restrict__ bn2_sq,
                                                const float* __restrict__ g2, const float* __restrict__ b2,
                                                float* __restrict__ pooled, float invN) {
    const int g = blockIdx.x & 127;
    const int sp = blockIdx.x >> 7;
    const int c = threadIdx.x;
    float mu = bn2_sum[c] * invN;
    float var = bn2_sq[c] * invN - mu * mu;
    float sc = g2[c] * rsqrtf(var + EPS_BN);
    float sh = fmaf(-mu, sc, b2[c]);
    const int i0 = gptr[g], i1 = gptr[g + 1];
    float acc = 0.f;
    for (int i = i0 + sp; i < i1; i += SPLIT) {
        int n = gnodes[i];
        float v = fmaf(out[(size_t)n * 128 + c], sc, sh) + h[(size_t)n * 128 + c];
        acc += softplus_fast(v);
    }
    if (acc != 0.f) atomicAdd(&pooled[g * 128 + c], acc);
}

// ---------------- head ----------------
__global__ __launch_bounds__(256) void k_head(const float* __restrict__ pooled, const int* __restrict__ gcount,
                                              const float* __restrict__ l1w, const float* __restrict__ l1b,
                                              const float* __restrict__ outw, const float* __restrict__ outb,
                                              float* __restrict__ dout) {
    __shared__ float p[128];
    __shared__ float red[256];
    const int g = blockIdx.x;
    const int j = threadIdx.x;
    if (j < 128) {
        float cnt = (float)max(gcount[g], 1);
        p[j] = pooled[g * 128 + j] / cnt;
    }
    __syncthreads();
    float acc = l1b[j];
    for (int k = 0; k < 128; k++) acc = fmaf(p[k], l1w[k * 256 + j], acc);
    red[j] = softplus_fast(acc) * outw[j];
    __syncthreads();
    for (int s = 128; s > 0; s >>= 1) {
        if (j < s) red[j] += red[j + s];
        __syncthreads();
    }
    if (j == 0) dout[g] = red[0] + outb[0];
}

// ---------------- launch ----------------
extern "C" void kernel_launch(void* const* d_in, const int* in_sizes, int n_in,
                              void* d_out, int out_size, void* d_ws, size_t ws_size,
                              hipStream_t stream) {
    const float* x        = (const float*)d_in[0];
    const float* hedge    = (const float*)d_in[1];
    const int*   iri      = (const int*)d_in[2];
    const int*   batch    = (const int*)d_in[3];
    const float* embed_w  = (const float*)d_in[5];
    const float* embed_b  = (const float*)d_in[6];
    const float* bembed_w = (const float*)d_in[7];
    const float* bembed_b = (const float*)d_in[8];
    const float* lin_w    = (const float*)d_in[9];
    const float* lin_b    = (const float*)d_in[10];
    const float* bn1_g    = (const float*)d_in[11];
    const float* bn1_b    = (const float*)d_in[12];
    const float* bn2_g    = (const float*)d_in[13];
    const float* bn2_b    = (const float*)d_in[14];
    const float* aggr_t   = (const float*)d_in[15];
    const float* l1_w     = (const float*)d_in[16];
    const float* l1_b     = (const float*)d_in[17];
    const float* out_w    = (const float*)d_in[18];
    const float* out_b    = (const float*)d_in[19];

    const int N   = in_sizes[0] / 92;
    const int NHE = in_sizes[1] / 40;
    const int E   = in_sizes[2] / 3;
    const int* idx0 = iri;
    const int* idx1 = iri + E;

    float* ws = (float*)d_ws;
    size_t off = 0;
    auto alloc = [&](size_t elems) -> float* {
        float* p = ws + off;
        off += (elems + 63) & ~(size_t)63;
        return p;
    };
    float* h      = alloc((size_t)N * 128);
    float* Apk    = alloc((size_t)N * 256);
    unsigned* Cp8 = (unsigned*)alloc((size_t)NHE * 64);
    unsigned short* embB  = (unsigned short*)alloc(6144);
    unsigned short* bembB = (unsigned short*)alloc(4096);
    unsigned short* waB   = (unsigned short*)alloc(16384);
    unsigned short* wcB   = (unsigned short*)alloc(16384);
    int*   rowptr = (int*)alloc((size_t)N + 1);
    int*   snode  = (int*)alloc((size_t)E + 8);
    int*   sidx1  = (int*)alloc((size_t)E + 8);
    int*   gptr   = (int*)alloc(129);
    int*   gnodes = (int*)alloc((size_t)N);
    float* outbuf = alloc((size_t)N * 128);
    // contiguous zero region
    float* zbase  = ws + off;
    int*   hist   = (int*)alloc((size_t)N);
    int*   fill   = (int*)alloc((size_t)N);
    int*   gfill  = (int*)alloc(128);
    float* bn1_sum = alloc(256);
    float* bn1_sq  = alloc(256);
    float* bn2_sum = alloc(128);
    float* bn2_sq  = alloc(128);
    float* pooled  = alloc(128 * 128);
    int*   gcount  = (int*)alloc(128);
    size_t zbytes = (size_t)((ws + off) - zbase) * sizeof(float);
    (void)ws_size;  // ~125MB; fit verified R1-R14

    hipMemsetAsync(zbase, 0, zbytes, stream);

    // frag-major bf16 weight prep + fused MFMA GEMM chains
    k_prepw<<<320, 256, 0, stream>>>(embed_w, bembed_w, lin_w, embB, bembB, waB, wcB);
    const int mtN   = (N + 31) / 32;
    const int mtNHE = (NHE + 31) / 32;
    mfma_fused<92, 3, 1><<<mtN, 256, 0, stream>>>(x, embB, embed_b, waB, lin_b, h, Apk, N);
    mfma_fused<40, 2, 2><<<mtNHE, 256, 0, stream>>>(hedge, bembB, bembed_b, wcB, nullptr, nullptr, Cp8, NHE);

    // CSR build
    k_hist2<<<(E + 255) / 256, 256, 0, stream>>>(idx0, batch, hist, gcount, E, N);
    k_scanall<<<1, 1024, 0, stream>>>(hist, rowptr, gcount, gptr, N);
    k_scatter2<<<(E + 255) / 256, 256, 0, stream>>>(idx0, idx1, batch, rowptr, gptr,
                                                    fill, gfill, sidx1, snode, gnodes, E, N);

    // BN1 stats
    const int STATS_BLOCKS = 2048;
    int per_slot = ((E + STATS_BLOCKS * 4 - 1) / (STATS_BLOCKS * 4) + 7) & ~7;
    k_stats<<<STATS_BLOCKS, 256, 0, stream>>>(Apk, Cp8, snode, sidx1, bn1_sum, bn1_sq, E, per_slot);

    // fused BN1-finalize + message + softmax aggregation
    k_aggr<<<(N + 3) / 4, 256, 0, stream>>>(Apk, Cp8, rowptr, sidx1, bn1_sum, bn1_sq,
                                            bn1_g, bn1_b, aggr_t, outbuf, 1.0f / (float)E, N);

    // BN2 stats + fused finalize/residual/softplus/pool
    k_bn2stats<<<(N + 63) / 64, 128, 0, stream>>>(outbuf, bn2_sum, bn2_sq, N);
    k_h2pool<16><<<128 * 16, 128, 0, stream>>>(outbuf, h, gptr, gnodes, bn2_sum, bn2_sq,
                                               bn2_g, bn2_b, pooled, 1.0f / (float)N);

    // head
    k_head<<<128, 256, 0, stream>>>(pooled, gcount, l1_w, l1_b, out_w, out_b, (float*)d_out);
}

// Round 16
// 591.948 us; speedup vs baseline: 1.0312x; 1.0124x over previous
//
#include <hip/hip_runtime.h>
#include <hip/hip_bf16.h>

// CrystalHypergraphConv — MI355X implementation.
//
// z[e] = A[idx0[e]] + C[idx1[e]];  A [N,256] bf16-packed; C [NHE,256]
// fp8-e4m3-packed. Lane l owns channels {2l,2l+1,128+2l,129+2l}.
//
// R15 -> R16: all f32 intermediates -> bf16 (Apk packed uint2/lane, h bf16,
// outbuf bf16 2-ch-per-dword). ~130MB less stream traffic across mfma_fused /
// k_stats / k_aggr / bn2stats / h2pool. Decode is 2-4 VALU per touch.
// k_aggr keeps the R13-proven 4-deep rolling prefetch (R14 regression lesson).

#define EPS_BN 1e-5f
#define LOG2E 1.4426950408889634f
#define LN2   0.6931471805599453f

typedef __attribute__((ext_vector_type(8))) short bf16x8;
typedef __attribute__((ext_vector_type(4))) float f32x4;
typedef __attribute__((ext_vector_type(2))) float f32x2;

__device__ __forceinline__ float fexp2(float x) {
#if __has_builtin(__builtin_amdgcn_exp2f)
    return __builtin_amdgcn_exp2f(x);
#else
    return __expf(x * LN2);
#endif
}
__device__ __forceinline__ float flog2(float x) {
#if __has_builtin(__builtin_amdgcn_logf)
    return __builtin_amdgcn_logf(x);
#else
    return __logf(x) * LOG2E;
#endif
}
__device__ __forceinline__ float softplus_fast(float x) {
    return LN2 * flog2(1.f + fexp2(x * LOG2E));
}

__device__ __forceinline__ unsigned short f2bf(float f) {
    unsigned u = __float_as_uint(f);
    unsigned r = (u + 0x7fffu + ((u >> 16) & 1u)) >> 16;   // RNE
    return (unsigned short)r;
}
__device__ __forceinline__ float bflo(unsigned u) { return __uint_as_float(u << 16); }
__device__ __forceinline__ float bfhi(unsigned u) { return __uint_as_float(u & 0xffff0000u); }
__device__ __forceinline__ float bfu16(unsigned short v) { return __uint_as_float(((unsigned)v) << 16); }
__device__ __forceinline__ unsigned pack2bf(float x, float y) {
    return (unsigned)f2bf(x) | ((unsigned)f2bf(y) << 16);
}

// ---- fp8 e4m3 encode/decode (OCP; HW path on gfx950) ----
#if __has_builtin(__builtin_amdgcn_cvt_pk_f32_fp8) && __has_builtin(__builtin_amdgcn_cvt_pk_fp8_f32)
#define HW_FP8 1
#else
#define HW_FP8 0
#endif

__device__ __forceinline__ unsigned char f2fp8(float f) {
#if HW_FP8
    int r = __builtin_amdgcn_cvt_pk_fp8_f32(f, f, 0, false);
    return (unsigned char)(r & 0xff);
#else
    unsigned u = __float_as_uint(f);
    unsigned s = (u >> 24) & 0x80u;
    float af = fabsf(f);
    if (!(af >= 0.015625f)) {
        int m = (int)rintf(af * 512.f);
        if (m > 7) m = 7;
        return (unsigned char)(s | (unsigned)m);
    }
    if (af > 448.f) return (unsigned char)(s | 0x7e);
    unsigned au = __float_as_uint(af);
    unsigned r = au + 0x7ffffu + ((au >> 20) & 1u);
    int e8 = (int)(r >> 23) - 120;
    unsigned m = (r >> 20) & 7u;
    if (e8 > 15 || (e8 == 15 && m == 7)) return (unsigned char)(s | 0x7e);
    return (unsigned char)(s | ((unsigned)e8 << 3) | m);
#endif
}

__device__ __forceinline__ void fp8quad(unsigned p, float& a, float& b, float& c, float& d) {
#if HW_FP8
    f32x2 lo = __builtin_amdgcn_cvt_pk_f32_fp8((int)p, false);
    f32x2 hi = __builtin_amdgcn_cvt_pk_f32_fp8((int)p, true);
    a = lo.x; b = lo.y; c = hi.x; d = hi.y;
#else
    auto dec = [](unsigned byte) -> float {
        unsigned s = (byte & 0x80u) << 24;
        unsigned em = byte & 0x7fu;
        float nrm = __uint_as_float(s | ((em << 20) + 0x3C000000u));
        float sub = __uint_as_float(s | 0x3F800000u) * (float)em * 0.001953125f;
        return (em >= 8) ? nrm : sub;
    };
    a = dec(p & 0xff); b = dec((p >> 8) & 0xff);
    c = dec((p >> 16) & 0xff); d = dec(p >> 24);
#endif
}

__device__ __forceinline__ int perm256(int j) {
    return (j < 128) ? ((j >> 1) * 4 + (j & 1)) : (((j - 128) >> 1) * 4 + 2 + (j & 1));
}

// ---------------- weight prep: frag-major bf16 B tables ----------------
__global__ __launch_bounds__(256) void k_prepw(const float* __restrict__ ew, const float* __restrict__ bw,
                                               const float* __restrict__ lw,
                                               unsigned short* __restrict__ embB, unsigned short* __restrict__ bembB,
                                               unsigned short* __restrict__ waB, unsigned short* __restrict__ wcB) {
    int i = blockIdx.x * 256 + threadIdx.x;          // 0..81919
    if (i >= 81920) return;
    unsigned short* dst;
    int f, NKC, CT, mode;
    if (i < 12288)      { dst = embB;  f = i;         NKC = 3; CT = 2; mode = 0; }
    else if (i < 20480) { dst = bembB; f = i - 12288; NKC = 2; CT = 2; mode = 1; }
    else if (i < 53248) { dst = waB;   f = i - 20480; NKC = 4; CT = 4; mode = 2; }
    else                { dst = wcB;   f = i - 53248; NKC = 4; CT = 4; mode = 3; }
    int j = f & 7, l = (f >> 3) & 63;
    int r2 = f >> 9;
    int c = r2 % CT;
    int r3 = r2 / CT;
    int kc = r3 % NKC, w = r3 / NKC;
    int k = kc * 32 + ((l >> 4) & 3) * 8 + j;
    int n = (w * CT + c) * 16 + (l & 15);
    float v;
    if (mode == 0)      v = (k < 92) ? ew[k * 128 + n] : 0.f;
    else if (mode == 1) v = (k < 40) ? bw[k * 128 + n] : 0.f;
    else if (mode == 2) v = lw[k * 256 + n] + lw[(k + 256) * 256 + n];
    else                v = lw[(k + 128) * 256 + n];
    dst[f] = f2bf(v);
}

// ---------------- fused 2-stage MFMA GEMM ----------------
// OMODE2: 1 = bf16-packed A + bf16 h out; 2 = fp8-packed C out
template<int KIN, int NKC1, int OMODE2>
__global__ __launch_bounds__(256) void mfma_fused(
    const float* __restrict__ in, const unsigned short* __restrict__ B1, const float* __restrict__ bias1,
    const unsigned short* __restrict__ B2, const float* __restrict__ bias2,
    unsigned short* __restrict__ hout, void* __restrict__ out2, int M)
{
    const int r0 = blockIdx.x * 32;
    const int t = threadIdx.x;
    const int w = t >> 6;
    const int l = t & 63;
    const int m = l & 15, q = l >> 4;

    __shared__ __align__(16) unsigned short als[32 * NKC1 * 32];
    __shared__ __align__(16) unsigned short hls[32 * 136];

    const int KP = NKC1 * 32;
    for (int i = t; i < 32 * KP; i += 256) {
        int r = i / KP, k = i - r * KP;
        int gr = r0 + r;
        float v = (gr < M && k < KIN) ? in[(size_t)gr * KIN + k] : 0.f;
        int idx = (((r >> 4) * NKC1 + (k >> 5)) * 64 + ((k >> 3) & 3) * 16 + (r & 15)) * 8 + (k & 7);
        als[idx] = f2bf(v);
    }
    bf16x8 b1[NKC1][2];
    const bf16x8* B1f = (const bf16x8*)B1;
#pragma unroll
    for (int kc = 0; kc < NKC1; kc++)
#pragma unroll
        for (int c = 0; c < 2; c++)
            b1[kc][c] = B1f[((w * NKC1 + kc) * 2 + c) * 64 + l];
    __syncthreads();

    f32x4 acc1[2][2];
#pragma unroll
    for (int c = 0; c < 2; c++) { acc1[c][0] = (f32x4){0.f,0.f,0.f,0.f}; acc1[c][1] = (f32x4){0.f,0.f,0.f,0.f}; }
    const bf16x8* af = (const bf16x8*)als;
#pragma unroll
    for (int kc = 0; kc < NKC1; kc++) {
        bf16x8 a0 = af[kc * 64 + l];
        bf16x8 a1 = af[(NKC1 + kc) * 64 + l];
#pragma unroll
        for (int c = 0; c < 2; c++) {
            acc1[c][0] = __builtin_amdgcn_mfma_f32_16x16x32_bf16(a0, b1[kc][c], acc1[c][0], 0, 0, 0);
            acc1[c][1] = __builtin_amdgcn_mfma_f32_16x16x32_bf16(a1, b1[kc][c], acc1[c][1], 0, 0, 0);
        }
    }
#pragma unroll
    for (int c = 0; c < 2; c++) {
        int n1 = (w * 2 + c) * 16 + m;
        float bv = bias1[n1];
#pragma unroll
        for (int hh = 0; hh < 2; hh++) {
#pragma unroll
            for (int r = 0; r < 4; r++) {
                int row = hh * 16 + q * 4 + r;
                float val = acc1[c][hh][r] + bv;
                unsigned short bf = f2bf(val);
                hls[row * 136 + n1] = bf;
                if (OMODE2 == 1 && r0 + row < M) hout[(size_t)(r0 + row) * 128 + n1] = bf;
            }
        }
    }
    __syncthreads();

    bf16x8 b2[4][4];
    const bf16x8* B2f = (const bf16x8*)B2;
#pragma unroll
    for (int kc = 0; kc < 4; kc++)
#pragma unroll
        for (int c = 0; c < 4; c++)
            b2[kc][c] = B2f[((w * 4 + kc) * 4 + c) * 64 + l];

    f32x4 acc2[4][2];
#pragma unroll
    for (int c = 0; c < 4; c++) { acc2[c][0] = (f32x4){0.f,0.f,0.f,0.f}; acc2[c][1] = (f32x4){0.f,0.f,0.f,0.f}; }
#pragma unroll
    for (int kc = 0; kc < 4; kc++) {
        bf16x8 a0 = *(const bf16x8*)(hls + m * 136 + kc * 32 + q * 8);
        bf16x8 a1 = *(const bf16x8*)(hls + (m + 16) * 136 + kc * 32 + q * 8);
#pragma unroll
        for (int c = 0; c < 4; c++) {
            acc2[c][0] = __builtin_amdgcn_mfma_f32_16x16x32_bf16(a0, b2[kc][c], acc2[c][0], 0, 0, 0);
            acc2[c][1] = __builtin_amdgcn_mfma_f32_16x16x32_bf16(a1, b2[kc][c], acc2[c][1], 0, 0, 0);
        }
    }
#pragma unroll
    for (int c = 0; c < 4; c++) {
        int n = (w * 4 + c) * 16 + m;
        float bv = bias2 ? bias2[n] : 0.f;
        int pj = perm256(n);
#pragma unroll
        for (int hh = 0; hh < 2; hh++) {
#pragma unroll
            for (int r = 0; r < 4; r++) {
                int row = r0 + hh * 16 + q * 4 + r;
                if (row < M) {
                    float val = acc2[c][hh][r] + bv;
                    if (OMODE2 == 1) ((unsigned short*)out2)[(size_t)row * 256 + pj] = f2bf(val);
                    else             ((unsigned char*)out2)[(size_t)row * 256 + pj] = f2fp8(val);
                }
            }
        }
    }
}

// ---------------- histograms ----------------
__global__ __launch_bounds__(256) void k_hist2(const int* __restrict__ idx0, const int* __restrict__ batch,
                                               int* __restrict__ hist, int* __restrict__ gcount, int E, int N) {
    int i = blockIdx.x * 256 + threadIdx.x;
    if (i < E) atomicAdd(&hist[idx0[i]], 1);
    if (i < N) atomicAdd(&gcount[batch[i]], 1);
}

// ---------------- single-block scan ----------------
__global__ __launch_bounds__(1024) void k_scanall(const int* __restrict__ hist, int* __restrict__ rowptr,
                                                  const int* __restrict__ gcount, int* __restrict__ gptr, int N) {
    __shared__ int s[1024];
    const int t = threadIdx.x;
    const int PER = (N + 1023) >> 10;
    const int b0 = t * PER;
    const int b1 = min(b0 + PER, N);
    int sum = 0;
    for (int i = b0; i < b1; i++) sum += hist[i];
    s[t] = sum;
    __syncthreads();
    for (int ofs = 1; ofs < 1024; ofs <<= 1) {
        int v = (t >= ofs) ? s[t - ofs] : 0;
        __syncthreads();
        s[t] += v;
        __syncthreads();
    }
    int run = s[t] - sum;
    for (int i = b0; i < b1; i++) {
        run += hist[i];
        rowptr[i + 1] = run;
    }
    if (t == 0) rowptr[0] = 0;
    __syncthreads();
    int gv = (t < 128) ? gcount[t] : 0;
    s[t] = gv;
    __syncthreads();
    for (int ofs = 1; ofs < 128; ofs <<= 1) {
        int v = (t >= ofs && t < 128) ? s[t - ofs] : 0;
        __syncthreads();
        if (t < 128) s[t] += v;
        __syncthreads();
    }
    if (t < 128) gptr[t + 1] = s[t];
    if (t == 0) gptr[0] = 0;
}

// ---------------- merged scatter ----------------
__global__ __launch_bounds__(256) void k_scatter2(const int* __restrict__ idx0, const int* __restrict__ idx1,
                                                  const int* __restrict__ batch,
                                                  const int* __restrict__ rowptr, const int* __restrict__ gptr,
                                                  int* __restrict__ fill, int* __restrict__ gfill,
                                                  int* __restrict__ sidx1, int* __restrict__ snode,
                                                  int* __restrict__ gnodes, int E, int N) {
    int i = blockIdx.x * 256 + threadIdx.x;
    if (i < E) {
        int n = idx0[i];
        int pos = rowptr[n] + atomicAdd(&fill[n], 1);
        sidx1[pos] = idx1[i];
    }
    if (i < N) {
        int a = rowptr[i], b = rowptr[i + 1];
        for (int e = a; e < b; e++) snode[e] = i;
        int g = batch[i];
        int pos = gptr[g] + atomicAdd(&gfill[g], 1);
        gnodes[pos] = i;
    }
}

// ---------------- BN1 stats: run-amortized bf16 A, 8-wide batched fp8 gathers ----------------
__global__ __launch_bounds__(256) void k_stats(const uint2* __restrict__ A16, const unsigned* __restrict__ Cp8,
                                               const int* __restrict__ snode, const int* __restrict__ sidx1,
                                               float* __restrict__ gsum, float* __restrict__ gsq,
                                               int E, int per_slot) {
    __shared__ float4 lsm4[256], lsq4[256];
    const int t = threadIdx.x;
    const int s = t >> 6, l = t & 63;
    const long base = (long)(blockIdx.x * 4 + s) * per_slot;
    const int e0 = (int)min((long)E, base);
    const int e1 = (int)min((long)E, base + per_slot);
    float4 sm = {0.f, 0.f, 0.f, 0.f}, s2 = {0.f, 0.f, 0.f, 0.f};
    float4 csr = {0.f, 0.f, 0.f, 0.f};
    float4 a = {0.f, 0.f, 0.f, 0.f};
    int cur_n = -1, runk = 0;

    auto flush = [&]() {
        if (runk) {
            float fk = (float)runk;
            sm.x += fmaf(fk, a.x, csr.x);
            sm.y += fmaf(fk, a.y, csr.y);
            sm.z += fmaf(fk, a.z, csr.z);
            sm.w += fmaf(fk, a.w, csr.w);
            float t0 = fmaf(fk, a.x, 2.f * csr.x); s2.x = fmaf(a.x, t0, s2.x);
            float t1 = fmaf(fk, a.y, 2.f * csr.y); s2.y = fmaf(a.y, t1, s2.y);
            float t2 = fmaf(fk, a.z, 2.f * csr.z); s2.z = fmaf(a.z, t2, s2.z);
            float t3 = fmaf(fk, a.w, 2.f * csr.w); s2.w = fmaf(a.w, t3, s2.w);
        }
    };
    auto proc = [&](int n, unsigned p) {
        if (n != cur_n) {
            flush();
            uint2 a8 = A16[(size_t)n * 64 + l];
            a.x = bflo(a8.x); a.y = bfhi(a8.x); a.z = bflo(a8.y); a.w = bfhi(a8.y);
            cur_n = n; runk = 0;
            csr.x = 0.f; csr.y = 0.f; csr.z = 0.f; csr.w = 0.f;
        }
        float c0, c1, c2, c3;
        fp8quad(p, c0, c1, c2, c3);
        csr.x += c0; csr.y += c1; csr.z += c2; csr.w += c3;
        s2.x = fmaf(c0, c0, s2.x);
        s2.y = fmaf(c1, c1, s2.y);
        s2.z = fmaf(c2, c2, s2.z);
        s2.w = fmaf(c3, c3, s2.w);
        runk++;
    };

    int e = e0;
    for (; e + 8 <= e1; e += 8) {
        int4 nn0 = *(const int4*)(snode + e);
        int4 nn1 = *(const int4*)(snode + e + 4);
        int4 mm0 = *(const int4*)(sidx1 + e);
        int4 mm1 = *(const int4*)(sidx1 + e + 4);
        unsigned p0 = Cp8[(size_t)mm0.x * 64 + l];
        unsigned p1 = Cp8[(size_t)mm0.y * 64 + l];
        unsigned p2 = Cp8[(size_t)mm0.z * 64 + l];
        unsigned p3 = Cp8[(size_t)mm0.w * 64 + l];
        unsigned p4 = Cp8[(size_t)mm1.x * 64 + l];
        unsigned p5 = Cp8[(size_t)mm1.y * 64 + l];
        unsigned p6 = Cp8[(size_t)mm1.z * 64 + l];
        unsigned p7 = Cp8[(size_t)mm1.w * 64 + l];
        proc(nn0.x, p0); proc(nn0.y, p1); proc(nn0.z, p2); proc(nn0.w, p3);
        proc(nn1.x, p4); proc(nn1.y, p5); proc(nn1.z, p6); proc(nn1.w, p7);
    }
    for (; e < e1; e++) proc(snode[e], Cp8[(size_t)sidx1[e] * 64 + l]);
    flush();

    lsm4[t] = sm;
    lsq4[t] = s2;
    __syncthreads();
    const float* fm = (const float*)lsm4;
    const float* fq = (const float*)lsq4;
    float vs = fm[t] + fm[256 + t] + fm[512 + t] + fm[768 + t];
    float vq = fq[t] + fq[256 + t] + fq[512 + t] + fq[768 + t];
    atomicAdd(&gsum[t], vs);
    atomicAdd(&gsq[t], vq);
}

// ---------------- fused BN1-finalize + msg + segment softmax (4 waves/block, 1 node/wave) ----------------
__global__ __launch_bounds__(256) void k_aggr(const uint2* __restrict__ A16, const unsigned* __restrict__ Cp8,
                                              const int* __restrict__ rowptr, const int* __restrict__ sidx1,
                                              const float* __restrict__ bn1_sum, const float* __restrict__ bn1_sq,
                                              const float* __restrict__ g1, const float* __restrict__ b1,
                                              const float* __restrict__ tptr, unsigned* __restrict__ out,
                                              float invE, int N) {
    const int n = blockIdx.x * 4 + (threadIdx.x >> 6);
    if (n >= N) return;
    const int l = threadIdx.x & 63;
    const float t = tptr[0];
    const float4 sum4 = ((const float4*)bn1_sum)[l];
    const float4 sq4  = ((const float4*)bn1_sq)[l];
    const float2 gf = ((const float2*)g1)[l];
    const float2 gc = ((const float2*)(g1 + 128))[l];
    const float2 bf2 = ((const float2*)b1)[l];
    const float2 bc2 = ((const float2*)(b1 + 128))[l];
    auto mkss = [&](float sum, float sq, float gg, float bb, float& sc, float& sh) {
        float mu = sum * invE;
        float var = sq * invE - mu * mu;
        sc = gg * rsqrtf(var + EPS_BN);
        sh = fmaf(-mu, sc, bb);
    };
    float scx, shx, scy, shy, scz, shz, scw, shw;
    mkss(sum4.x, sq4.x, gf.x, bf2.x, scx, shx);
    mkss(sum4.y, sq4.y, gf.y, bf2.y, scy, shy);
    mkss(sum4.z, sq4.z, gc.x, bc2.x, scz, shz);
    mkss(sum4.w, sq4.w, gc.y, bc2.y, scw, shw);

    uint2 a8 = A16[(size_t)n * 64 + l];
    const float apx = bflo(a8.x), apy = bfhi(a8.x), apz = bflo(a8.y), apw = bfhi(a8.y);
    const float sfx = -scx * LOG2E, sfy = -scy * LOG2E;
    const float bfx = -fmaf(apx, scx, shx) * LOG2E;
    const float bfy = -fmaf(apy, scy, shy) * LOG2E;
    const float sczz = scz * LOG2E, scww = scw * LOG2E;
    const float bcz = fmaf(apz, scz, shz) * LOG2E;
    const float bcw = fmaf(apw, scw, shw) * LOG2E;

    const int e0 = rowptr[n], e1 = rowptr[n + 1];
    float den0 = 0.f, num0 = 0.f, den1 = 0.f, num1 = 0.f;

    auto proc = [&](unsigned p) {
        float c0, c1, c2, c3;
        fp8quad(p, c0, c1, c2, c3);
        float ef0 = fexp2(fmaf(c0, sfx, bfx));
        float ef1 = fexp2(fmaf(c1, sfy, bfy));
        float u0  = fexp2(fmaf(c2, sczz, bcz));
        float u1  = fexp2(fmaf(c3, scww, bcw));
        float sig0 = __builtin_amdgcn_rcpf(1.f + ef0);
        float sig1 = __builtin_amdgcn_rcpf(1.f + ef1);
        float M0 = sig0 * flog2(1.f + u0);
        float M1 = sig1 * flog2(1.f + u1);
        float w0 = fexp2(t * M0);
        float w1 = fexp2(t * M1);
        den0 += w0; num0 = fmaf(M0, w0, num0);
        den1 += w1; num1 = fmaf(M1, w1, num1);
    };

    if (e1 > e0) {
        unsigned cur[4];
        int cb = min(e1 - e0, 4);
#pragma unroll
        for (int i = 0; i < 4; i++)
            if (i < cb) cur[i] = Cp8[(size_t)sidx1[e0 + i] * 64 + l];
        for (int eb = e0; eb < e1; eb += 4) {
            int nb = min(max(e1 - (eb + 4), 0), 4);
            unsigned nxt[4];
#pragma unroll
            for (int i = 0; i < 4; i++)
                if (i < nb) nxt[i] = Cp8[(size_t)sidx1[eb + 4 + i] * 64 + l];
            int pb = min(e1 - eb, 4);
#pragma unroll
            for (int i = 0; i < 4; i++)
                if (i < pb) proc(cur[i]);
#pragma unroll
            for (int i = 0; i < 4; i++) cur[i] = nxt[i];
        }
    }
    float ox = (e1 > e0) ? LN2 * num0 / den0 : 0.f;
    float oy = (e1 > e0) ? LN2 * num1 / den1 : 0.f;
    out[(size_t)n * 64 + l] = pack2bf(ox, oy);       // channels 2l, 2l+1 as bf16
}

// ---------------- BN2 stats (bf16 outbuf) ----------------
__global__ __launch_bounds__(128) void k_bn2stats(const unsigned short* __restrict__ out, float* __restrict__ sum,
                                                  float* __restrict__ sq, int N) {
    const int c = threadIdx.x;
    const int n0 = blockIdx.x * 64;
    const int nend = min(n0 + 64, N);
    float sm = 0.f, s2 = 0.f;
    for (int n = n0; n < nend; n++) {
        float v = bfu16(out[(size_t)n * 128 + c]);
        sm += v;
        s2 = fmaf(v, v, s2);
    }
    atomicAdd(&sum[c], sm);
    atomicAdd(&sq[c], s2);
}

// ---------------- fused BN2-finalize + residual+softplus + mean-pool (bf16 inputs) ----------------
template<int SPLIT>
__global__ __launch_bounds__(128) void k_h2pool(const unsigned short* __restrict__ out,
                                                const unsigned short* __restrict__ h,
                                                const int* __restrict__ gptr, const int* __restrict__ gnodes,
                                                const float* __restrict__ bn2_sum, const float* __restrict__ bn2_sq,
                                                const float* __restrict__ g2, const float* __restrict__ b2,
                                                float* __restrict__ pooled, float invN) {
    const int g = blockIdx.x & 127;
    const int sp = blockIdx.x >> 7;
    const int c = threadIdx.x;
    float mu = bn2_sum[c] * invN;
    float var = bn2_sq[c] * invN - mu * mu;
    float sc = g2[c] * rsqrtf(var + EPS_BN);
    float sh = fmaf(-mu, sc, b2[c]);
    const int i0 = gptr[g], i1 = gptr[g + 1];
    float acc = 0.f;
    for (int i = i0 + sp; i < i1; i += SPLIT) {
        int n = gnodes[i];
        float v = fmaf(bfu16(out[(size_t)n * 128 + c]), sc, sh) + bfu16(h[(size_t)n * 128 + c]);
        acc += softplus_fast(v);
    }
    if (acc != 0.f) atomicAdd(&pooled[g * 128 + c], acc);
}

// ---------------- head ----------------
__global__ __launch_bounds__(256) void k_head(const float* __restrict__ pooled, const int* __restrict__ gcount,
                                              const float* __restrict__ l1w, const float* __restrict__ l1b,
                                              const float* __restrict__ outw, const float* __restrict__ outb,
                                              float* __restrict__ dout) {
    __shared__ float p[128];
    __shared__ float red[256];
    const int g = blockIdx.x;
    const int j = threadIdx.x;
    if (j < 128) {
        float cnt = (float)max(gcount[g], 1);
        p[j] = pooled[g * 128 + j] / cnt;
    }
    __syncthreads();
    float acc = l1b[j];
    for (int k = 0; k < 128; k++) acc = fmaf(p[k], l1w[k * 256 + j], acc);
    red[j] = softplus_fast(acc) * outw[j];
    __syncthreads();
    for (int s = 128; s > 0; s >>= 1) {
        if (j < s) red[j] += red[j + s];
        __syncthreads();
    }
    if (j == 0) dout[g] = red[0] + outb[0];
}

// ---------------- launch ----------------
extern "C" void kernel_launch(void* const* d_in, const int* in_sizes, int n_in,
                              void* d_out, int out_size, void* d_ws, size_t ws_size,
                              hipStream_t stream) {
    const float* x        = (const float*)d_in[0];
    const float* hedge    = (const float*)d_in[1];
    const int*   iri      = (const int*)d_in[2];
    const int*   batch    = (const int*)d_in[3];
    const float* embed_w  = (const float*)d_in[5];
    const float* embed_b  = (const float*)d_in[6];
    const float* bembed_w = (const float*)d_in[7];
    const float* bembed_b = (const float*)d_in[8];
    const float* lin_w    = (const float*)d_in[9];
    const float* lin_b    = (const float*)d_in[10];
    const float* bn1_g    = (const float*)d_in[11];
    const float* bn1_b    = (const float*)d_in[12];
    const float* bn2_g    = (const float*)d_in[13];
    const float* bn2_b    = (const float*)d_in[14];
    const float* aggr_t   = (const float*)d_in[15];
    const float* l1_w     = (const float*)d_in[16];
    const float* l1_b     = (const float*)d_in[17];
    const float* out_w    = (const float*)d_in[18];
    const float* out_b    = (const float*)d_in[19];

    const int N   = in_sizes[0] / 92;
    const int NHE = in_sizes[1] / 40;
    const int E   = in_sizes[2] / 3;
    const int* idx0 = iri;
    const int* idx1 = iri + E;

    float* ws = (float*)d_ws;
    size_t off = 0;
    auto alloc = [&](size_t elems) -> float* {
        float* p = ws + off;
        off += (elems + 63) & ~(size_t)63;
        return p;
    };
    unsigned short* h16 = (unsigned short*)alloc((size_t)N * 64);   // N*128 bf16
    uint2* A16    = (uint2*)alloc((size_t)N * 128);                 // N*256 bf16 packed
    unsigned* Cp8 = (unsigned*)alloc((size_t)NHE * 64);             // NHE*256 fp8 packed
    unsigned short* embB  = (unsigned short*)alloc(6144);
    unsigned short* bembB = (unsigned short*)alloc(4096);
    unsigned short* waB   = (unsigned short*)alloc(16384);
    unsigned short* wcB   = (unsigned short*)alloc(16384);
    int*   rowptr = (int*)alloc((size_t)N + 1);
    int*   snode  = (int*)alloc((size_t)E + 8);
    int*   sidx1  = (int*)alloc((size_t)E + 8);
    int*   gptr   = (int*)alloc(129);
    int*   gnodes = (int*)alloc((size_t)N);
    unsigned* outbuf = (unsigned*)alloc((size_t)N * 64);            // N*128 bf16
    // contiguous zero region
    float* zbase  = ws + off;
    int*   hist   = (int*)alloc((size_t)N);
    int*   fill   = (int*)alloc((size_t)N);
    int*   gfill  = (int*)alloc(128);
    float* bn1_sum = alloc(256);
    float* bn1_sq  = alloc(256);
    float* bn2_sum = alloc(128);
    float* bn2_sq  = alloc(128);
    float* pooled  = alloc(128 * 128);
    int*   gcount  = (int*)alloc(128);
    size_t zbytes = (size_t)((ws + off) - zbase) * sizeof(float);
    (void)ws_size;  // ~80MB; fit verified R1-R15 at larger sizes

    hipMemsetAsync(zbase, 0, zbytes, stream);

    // frag-major bf16 weight prep + fused MFMA GEMM chains
    k_prepw<<<320, 256, 0, stream>>>(embed_w, bembed_w, lin_w, embB, bembB, waB, wcB);
    const int mtN   = (N + 31) / 32;
    const int mtNHE = (NHE + 31) / 32;
    mfma_fused<92, 3, 1><<<mtN, 256, 0, stream>>>(x, embB, embed_b, waB, lin_b, h16, A16, N);
    mfma_fused<40, 2, 2><<<mtNHE, 256, 0, stream>>>(hedge, bembB, bembed_b, wcB, nullptr, nullptr, Cp8, NHE);

    // CSR build
    k_hist2<<<(E + 255) / 256, 256, 0, stream>>>(idx0, batch, hist, gcount, E, N);
    k_scanall<<<1, 1024, 0, stream>>>(hist, rowptr, gcount, gptr, N);
    k_scatter2<<<(E + 255) / 256, 256, 0, stream>>>(idx0, idx1, batch, rowptr, gptr,
                                                    fill, gfill, sidx1, snode, gnodes, E, N);

    // BN1 stats
    const int STATS_BLOCKS = 2048;
    int per_slot = ((E + STATS_BLOCKS * 4 - 1) / (STATS_BLOCKS * 4) + 7) & ~7;
    k_stats<<<STATS_BLOCKS, 256, 0, stream>>>(A16, Cp8, snode, sidx1, bn1_sum, bn1_sq, E, per_slot);

    // fused BN1-finalize + message + softmax aggregation
    k_aggr<<<(N + 3) / 4, 256, 0, stream>>>(A16, Cp8, rowptr, sidx1, bn1_sum, bn1_sq,
                                            bn1_g, bn1_b, aggr_t, outbuf, 1.0f / (float)E, N);

    // BN2 stats + fused finalize/residual/softplus/pool
    k_bn2stats<<<(N + 63) / 64, 128, 0, stream>>>((const unsigned short*)outbuf, bn2_sum, bn2_sq, N);
    k_h2pool<16><<<128 * 16, 128, 0, stream>>>((const unsigned short*)outbuf, h16, gptr, gnodes,
                                               bn2_sum, bn2_sq, bn2_g, bn2_b, pooled, 1.0f / (float)N);

    // head
    k_head<<<128, 256, 0, stream>>>(pooled, gcount, l1_w, l1_b, out_w, out_b, (float*)d_out);
}

// Round 17
// 587.288 us; speedup vs baseline: 1.0394x; 1.0079x over previous
//
#include <hip/hip_runtime.h>
#include <hip/hip_bf16.h>

// CrystalHypergraphConv — MI355X implementation.
//
// z[e] = A[idx0[e]] + C[idx1[e]];  A [N,256] bf16-packed; C [NHE,256]
// fp8-e4m3-packed. Lane l owns channels {2l,2l+1,128+2l,129+2l}.
//
// R16 -> R17: snode eliminated. k_stats derives the node for each CSR
// position from rowptr (wave-uniform binary search per slot + boundary
// compares) instead of reading a precomputed snode array; k_scatter2 loses
// its serial 800k-scattered-write snode fill. k_aggr unchanged (trans-pipe
// floor, VALUBusy 78%).

#define EPS_BN 1e-5f
#define LOG2E 1.4426950408889634f
#define LN2   0.6931471805599453f

typedef __attribute__((ext_vector_type(8))) short bf16x8;
typedef __attribute__((ext_vector_type(4))) float f32x4;
typedef __attribute__((ext_vector_type(2))) float f32x2;

__device__ __forceinline__ float fexp2(float x) {
#if __has_builtin(__builtin_amdgcn_exp2f)
    return __builtin_amdgcn_exp2f(x);
#else
    return __expf(x * LN2);
#endif
}
__device__ __forceinline__ float flog2(float x) {
#if __has_builtin(__builtin_amdgcn_logf)
    return __builtin_amdgcn_logf(x);
#else
    return __logf(x) * LOG2E;
#endif
}
__device__ __forceinline__ float softplus_fast(float x) {
    return LN2 * flog2(1.f + fexp2(x * LOG2E));
}

__device__ __forceinline__ unsigned short f2bf(float f) {
    unsigned u = __float_as_uint(f);
    unsigned r = (u + 0x7fffu + ((u >> 16) & 1u)) >> 16;   // RNE
    return (unsigned short)r;
}
__device__ __forceinline__ float bflo(unsigned u) { return __uint_as_float(u << 16); }
__device__ __forceinline__ float bfhi(unsigned u) { return __uint_as_float(u & 0xffff0000u); }
__device__ __forceinline__ float bfu16(unsigned short v) { return __uint_as_float(((unsigned)v) << 16); }
__device__ __forceinline__ unsigned pack2bf(float x, float y) {
    return (unsigned)f2bf(x) | ((unsigned)f2bf(y) << 16);
}

// ---- fp8 e4m3 encode/decode (OCP; HW path on gfx950) ----
#if __has_builtin(__builtin_amdgcn_cvt_pk_f32_fp8) && __has_builtin(__builtin_amdgcn_cvt_pk_fp8_f32)
#define HW_FP8 1
#else
#define HW_FP8 0
#endif

__device__ __forceinline__ unsigned char f2fp8(float f) {
#if HW_FP8
    int r = __builtin_amdgcn_cvt_pk_fp8_f32(f, f, 0, false);
    return (unsigned char)(r & 0xff);
#else
    unsigned u = __float_as_uint(f);
    unsigned s = (u >> 24) & 0x80u;
    float af = fabsf(f);
    if (!(af >= 0.015625f)) {
        int m = (int)rintf(af * 512.f);
        if (m > 7) m = 7;
        return (unsigned char)(s | (unsigned)m);
    }
    if (af > 448.f) return (unsigned char)(s | 0x7e);
    unsigned au = __float_as_uint(af);
    unsigned r = au + 0x7ffffu + ((au >> 20) & 1u);
    int e8 = (int)(r >> 23) - 120;
    unsigned m = (r >> 20) & 7u;
    if (e8 > 15 || (e8 == 15 && m == 7)) return (unsigned char)(s | 0x7e);
    return (unsigned char)(s | ((unsigned)e8 << 3) | m);
#endif
}

__device__ __forceinline__ void fp8quad(unsigned p, float& a, float& b, float& c, float& d) {
#if HW_FP8
    f32x2 lo = __builtin_amdgcn_cvt_pk_f32_fp8((int)p, false);
    f32x2 hi = __builtin_amdgcn_cvt_pk_f32_fp8((int)p, true);
    a = lo.x; b = lo.y; c = hi.x; d = hi.y;
#else
    auto dec = [](unsigned byte) -> float {
        unsigned s = (byte & 0x80u) << 24;
        unsigned em = byte & 0x7fu;
        float nrm = __uint_as_float(s | ((em << 20) + 0x3C000000u));
        float sub = __uint_as_float(s | 0x3F800000u) * (float)em * 0.001953125f;
        return (em >= 8) ? nrm : sub;
    };
    a = dec(p & 0xff); b = dec((p >> 8) & 0xff);
    c = dec((p >> 16) & 0xff); d = dec(p >> 24);
#endif
}

__device__ __forceinline__ int perm256(int j) {
    return (j < 128) ? ((j >> 1) * 4 + (j & 1)) : (((j - 128) >> 1) * 4 + 2 + (j & 1));
}

// ---------------- weight prep: frag-major bf16 B tables ----------------
__global__ __launch_bounds__(256) void k_prepw(const float* __restrict__ ew, const float* __restrict__ bw,
                                               const float* __restrict__ lw,
                                               unsigned short* __restrict__ embB, unsigned short* __restrict__ bembB,
                                               unsigned short* __restrict__ waB, unsigned short* __restrict__ wcB) {
    int i = blockIdx.x * 256 + threadIdx.x;          // 0..81919
    if (i >= 81920) return;
    unsigned short* dst;
    int f, NKC, CT, mode;
    if (i < 12288)      { dst = embB;  f = i;         NKC = 3; CT = 2; mode = 0; }
    else if (i < 20480) { dst = bembB; f = i - 12288; NKC = 2; CT = 2; mode = 1; }
    else if (i < 53248) { dst = waB;   f = i - 20480; NKC = 4; CT = 4; mode = 2; }
    else                { dst = wcB;   f = i - 53248; NKC = 4; CT = 4; mode = 3; }
    int j = f & 7, l = (f >> 3) & 63;
    int r2 = f >> 9;
    int c = r2 % CT;
    int r3 = r2 / CT;
    int kc = r3 % NKC, w = r3 / NKC;
    int k = kc * 32 + ((l >> 4) & 3) * 8 + j;
    int n = (w * CT + c) * 16 + (l & 15);
    float v;
    if (mode == 0)      v = (k < 92) ? ew[k * 128 + n] : 0.f;
    else if (mode == 1) v = (k < 40) ? bw[k * 128 + n] : 0.f;
    else if (mode == 2) v = lw[k * 256 + n] + lw[(k + 256) * 256 + n];
    else                v = lw[(k + 128) * 256 + n];
    dst[f] = f2bf(v);
}

// ---------------- fused 2-stage MFMA GEMM ----------------
// OMODE2: 1 = bf16-packed A + bf16 h out; 2 = fp8-packed C out
template<int KIN, int NKC1, int OMODE2>
__global__ __launch_bounds__(256) void mfma_fused(
    const float* __restrict__ in, const unsigned short* __restrict__ B1, const float* __restrict__ bias1,
    const unsigned short* __restrict__ B2, const float* __restrict__ bias2,
    unsigned short* __restrict__ hout, void* __restrict__ out2, int M)
{
    const int r0 = blockIdx.x * 32;
    const int t = threadIdx.x;
    const int w = t >> 6;
    const int l = t & 63;
    const int m = l & 15, q = l >> 4;

    __shared__ __align__(16) unsigned short als[32 * NKC1 * 32];
    __shared__ __align__(16) unsigned short hls[32 * 136];

    const int KP = NKC1 * 32;
    for (int i = t; i < 32 * KP; i += 256) {
        int r = i / KP, k = i - r * KP;
        int gr = r0 + r;
        float v = (gr < M && k < KIN) ? in[(size_t)gr * KIN + k] : 0.f;
        int idx = (((r >> 4) * NKC1 + (k >> 5)) * 64 + ((k >> 3) & 3) * 16 + (r & 15)) * 8 + (k & 7);
        als[idx] = f2bf(v);
    }
    bf16x8 b1[NKC1][2];
    const bf16x8* B1f = (const bf16x8*)B1;
#pragma unroll
    for (int kc = 0; kc < NKC1; kc++)
#pragma unroll
        for (int c = 0; c < 2; c++)
            b1[kc][c] = B1f[((w * NKC1 + kc) * 2 + c) * 64 + l];
    __syncthreads();

    f32x4 acc1[2][2];
#pragma unroll
    for (int c = 0; c < 2; c++) { acc1[c][0] = (f32x4){0.f,0.f,0.f,0.f}; acc1[c][1] = (f32x4){0.f,0.f,0.f,0.f}; }
    const bf16x8* af = (const bf16x8*)als;
#pragma unroll
    for (int kc = 0; kc < NKC1; kc++) {
        bf16x8 a0 = af[kc * 64 + l];
        bf16x8 a1 = af[(NKC1 + kc) * 64 + l];
#pragma unroll
        for (int c = 0; c < 2; c++) {
            acc1[c][0] = __builtin_amdgcn_mfma_f32_16x16x32_bf16(a0, b1[kc][c], acc1[c][0], 0, 0, 0);
            acc1[c][1] = __builtin_amdgcn_mfma_f32_16x16x32_bf16(a1, b1[kc][c], acc1[c][1], 0, 0, 0);
        }
    }
#pragma unroll
    for (int c = 0; c < 2; c++) {
        int n1 = (w * 2 + c) * 16 + m;
        float bv = bias1[n1];
#pragma unroll
        for (int hh = 0; hh < 2; hh++) {
#pragma unroll
            for (int r = 0; r < 4; r++) {
                int row = hh * 16 + q * 4 + r;
                float val = acc1[c][hh][r] + bv;
                unsigned short bf = f2bf(val);
                hls[row * 136 + n1] = bf;
                if (OMODE2 == 1 && r0 + row < M) hout[(size_t)(r0 + row) * 128 + n1] = bf;
            }
        }
    }
    __syncthreads();

    bf16x8 b2[4][4];
    const bf16x8* B2f = (const bf16x8*)B2;
#pragma unroll
    for (int kc = 0; kc < 4; kc++)
#pragma unroll
        for (int c = 0; c < 4; c++)
            b2[kc][c] = B2f[((w * 4 + kc) * 4 + c) * 64 + l];

    f32x4 acc2[4][2];
#pragma unroll
    for (int c = 0; c < 4; c++) { acc2[c][0] = (f32x4){0.f,0.f,0.f,0.f}; acc2[c][1] = (f32x4){0.f,0.f,0.f,0.f}; }
#pragma unroll
    for (int kc = 0; kc < 4; kc++) {
        bf16x8 a0 = *(const bf16x8*)(hls + m * 136 + kc * 32 + q * 8);
        bf16x8 a1 = *(const bf16x8*)(hls + (m + 16) * 136 + kc * 32 + q * 8);
#pragma unroll
        for (int c = 0; c < 4; c++) {
            acc2[c][0] = __builtin_amdgcn_mfma_f32_16x16x32_bf16(a0, b2[kc][c], acc2[c][0], 0, 0, 0);
            acc2[c][1] = __builtin_amdgcn_mfma_f32_16x16x32_bf16(a1, b2[kc][c], acc2[c][1], 0, 0, 0);
        }
    }
#pragma unroll
    for (int c = 0; c < 4; c++) {
        int n = (w * 4 + c) * 16 + m;
        float bv = bias2 ? bias2[n] : 0.f;
        int pj = perm256(n);
#pragma unroll
        for (int hh = 0; hh < 2; hh++) {
#pragma unroll
            for (int r = 0; r < 4; r++) {
                int row = r0 + hh * 16 + q * 4 + r;
                if (row < M) {
                    float val = acc2[c][hh][r] + bv;
                    if (OMODE2 == 1) ((unsigned short*)out2)[(size_t)row * 256 + pj] = f2bf(val);
                    else             ((unsigned char*)out2)[(size_t)row * 256 + pj] = f2fp8(val);
                }
            }
        }
    }
}

// ---------------- histograms ----------------
__global__ __launch_bounds__(256) void k_hist2(const int* __restrict__ idx0, const int* __restrict__ batch,
                                               int* __restrict__ hist, int* __restrict__ gcount, int E, int N) {
    int i = blockIdx.x * 256 + threadIdx.x;
    if (i < E) atomicAdd(&hist[idx0[i]], 1);
    if (i < N) atomicAdd(&gcount[batch[i]], 1);
}

// ---------------- single-block scan ----------------
__global__ __launch_bounds__(1024) void k_scanall(const int* __restrict__ hist, int* __restrict__ rowptr,
                                                  const int* __restrict__ gcount, int* __restrict__ gptr, int N) {
    __shared__ int s[1024];
    const int t = threadIdx.x;
    const int PER = (N + 1023) >> 10;
    const int b0 = t * PER;
    const int b1 = min(b0 + PER, N);
    int sum = 0;
    for (int i = b0; i < b1; i++) sum += hist[i];
    s[t] = sum;
    __syncthreads();
    for (int ofs = 1; ofs < 1024; ofs <<= 1) {
        int v = (t >= ofs) ? s[t - ofs] : 0;
        __syncthreads();
        s[t] += v;
        __syncthreads();
    }
    int run = s[t] - sum;
    for (int i = b0; i < b1; i++) {
        run += hist[i];
        rowptr[i + 1] = run;
    }
    if (t == 0) rowptr[0] = 0;
    __syncthreads();
    int gv = (t < 128) ? gcount[t] : 0;
    s[t] = gv;
    __syncthreads();
    for (int ofs = 1; ofs < 128; ofs <<= 1) {
        int v = (t >= ofs && t < 128) ? s[t - ofs] : 0;
        __syncthreads();
        if (t < 128) s[t] += v;
        __syncthreads();
    }
    if (t < 128) gptr[t + 1] = s[t];
    if (t == 0) gptr[0] = 0;
}

// ---------------- merged scatter (no snode fill) ----------------
__global__ __launch_bounds__(256) void k_scatter2(const int* __restrict__ idx0, const int* __restrict__ idx1,
                                                  const int* __restrict__ batch,
                                                  const int* __restrict__ rowptr, const int* __restrict__ gptr,
                                                  int* __restrict__ fill, int* __restrict__ gfill,
                                                  int* __restrict__ sidx1, int* __restrict__ gnodes, int E, int N) {
    int i = blockIdx.x * 256 + threadIdx.x;
    if (i < E) {
        int n = idx0[i];
        int pos = rowptr[n] + atomicAdd(&fill[n], 1);
        sidx1[pos] = idx1[i];
    }
    if (i < N) {
        int g = batch[i];
        int pos = gptr[g] + atomicAdd(&gfill[g], 1);
        gnodes[pos] = i;
    }
}

// ---------------- BN1 stats: run-amortized bf16 A via rowptr boundaries, 8-wide fp8 gathers ----------------
__global__ __launch_bounds__(256) void k_stats(const uint2* __restrict__ A16, const unsigned* __restrict__ Cp8,
                                               const int* __restrict__ rowptr, const int* __restrict__ sidx1,
                                               float* __restrict__ gsum, float* __restrict__ gsq,
                                               int E, int N, int per_slot) {
    __shared__ float4 lsm4[256], lsq4[256];
    const int t = threadIdx.x;
    const int s = t >> 6, l = t & 63;
    const long base = (long)(blockIdx.x * 4 + s) * per_slot;
    const int e0 = (int)min((long)E, base);
    const int e1 = (int)min((long)E, base + per_slot);
    float4 sm = {0.f, 0.f, 0.f, 0.f}, s2 = {0.f, 0.f, 0.f, 0.f};
    float4 csr = {0.f, 0.f, 0.f, 0.f};
    float4 a = {0.f, 0.f, 0.f, 0.f};
    int cur_n = 0, bound = 0, runk = 0;

    auto flush = [&]() {
        if (runk) {
            float fk = (float)runk;
            sm.x += fmaf(fk, a.x, csr.x);
            sm.y += fmaf(fk, a.y, csr.y);
            sm.z += fmaf(fk, a.z, csr.z);
            sm.w += fmaf(fk, a.w, csr.w);
            float t0 = fmaf(fk, a.x, 2.f * csr.x); s2.x = fmaf(a.x, t0, s2.x);
            float t1 = fmaf(fk, a.y, 2.f * csr.y); s2.y = fmaf(a.y, t1, s2.y);
            float t2 = fmaf(fk, a.z, 2.f * csr.z); s2.z = fmaf(a.z, t2, s2.z);
            float t3 = fmaf(fk, a.w, 2.f * csr.w); s2.w = fmaf(a.w, t3, s2.w);
        }
    };
    auto loadA = [&](int n) {
        uint2 a8 = A16[(size_t)n * 64 + l];
        a.x = bflo(a8.x); a.y = bfhi(a8.x); a.z = bflo(a8.y); a.w = bfhi(a8.y);
    };

    if (e0 < e1) {
        // wave-uniform binary search: cur_n = max n with rowptr[n] <= e0
        int lo = 0, hi = N;
        while (lo + 1 < hi) {
            int mid = (lo + hi) >> 1;
            if (rowptr[mid] <= e0) lo = mid; else hi = mid;
        }
        cur_n = lo;
        bound = rowptr[cur_n + 1];
        loadA(cur_n);
    }

    auto proc = [&](int e, unsigned p) {
        if (e >= bound) {                            // wave-uniform
            flush();
            do { cur_n++; bound = rowptr[cur_n + 1]; } while (bound <= e);
            loadA(cur_n);
            runk = 0;
            csr.x = 0.f; csr.y = 0.f; csr.z = 0.f; csr.w = 0.f;
        }
        float c0, c1, c2, c3;
        fp8quad(p, c0, c1, c2, c3);
        csr.x += c0; csr.y += c1; csr.z += c2; csr.w += c3;
        s2.x = fmaf(c0, c0, s2.x);
        s2.y = fmaf(c1, c1, s2.y);
        s2.z = fmaf(c2, c2, s2.z);
        s2.w = fmaf(c3, c3, s2.w);
        runk++;
    };

    int e = e0;
    for (; e + 8 <= e1; e += 8) {
        int4 mm0 = *(const int4*)(sidx1 + e);
        int4 mm1 = *(const int4*)(sidx1 + e + 4);
        unsigned p0 = Cp8[(size_t)mm0.x * 64 + l];
        unsigned p1 = Cp8[(size_t)mm0.y * 64 + l];
        unsigned p2 = Cp8[(size_t)mm0.z * 64 + l];
        unsigned p3 = Cp8[(size_t)mm0.w * 64 + l];
        unsigned p4 = Cp8[(size_t)mm1.x * 64 + l];
        unsigned p5 = Cp8[(size_t)mm1.y * 64 + l];
        unsigned p6 = Cp8[(size_t)mm1.z * 64 + l];
        unsigned p7 = Cp8[(size_t)mm1.w * 64 + l];
        proc(e, p0); proc(e + 1, p1); proc(e + 2, p2); proc(e + 3, p3);
        proc(e + 4, p4); proc(e + 5, p5); proc(e + 6, p6); proc(e + 7, p7);
    }
    for (; e < e1; e++) proc(e, Cp8[(size_t)sidx1[e] * 64 + l]);
    flush();

    lsm4[t] = sm;
    lsq4[t] = s2;
    __syncthreads();
    const float* fm = (const float*)lsm4;
    const float* fq = (const float*)lsq4;
    float vs = fm[t] + fm[256 + t] + fm[512 + t] + fm[768 + t];
    float vq = fq[t] + fq[256 + t] + fq[512 + t] + fq[768 + t];
    atomicAdd(&gsum[t], vs);
    atomicAdd(&gsq[t], vq);
}

// ---------------- fused BN1-finalize + msg + segment softmax (4 waves/block, 1 node/wave) ----------------
__global__ __launch_bounds__(256) void k_aggr(const uint2* __restrict__ A16, const unsigned* __restrict__ Cp8,
                                              const int* __restrict__ rowptr, const int* __restrict__ sidx1,
                                              const float* __restrict__ bn1_sum, const float* __restrict__ bn1_sq,
                                              const float* __restrict__ g1, const float* __restrict__ b1,
                                              const float* __restrict__ tptr, unsigned* __restrict__ out,
                                              float invE, int N) {
    const int n = blockIdx.x * 4 + (threadIdx.x >> 6);
    if (n >= N) return;
    const int l = threadIdx.x & 63;
    const float t = tptr[0];
    const float4 sum4 = ((const float4*)bn1_sum)[l];
    const float4 sq4  = ((const float4*)bn1_sq)[l];
    const float2 gf = ((const float2*)g1)[l];
    const float2 gc = ((const float2*)(g1 + 128))[l];
    const float2 bf2 = ((const float2*)b1)[l];
    const float2 bc2 = ((const float2*)(b1 + 128))[l];
    auto mkss = [&](float sum, float sq, float gg, float bb, float& sc, float& sh) {
        float mu = sum * invE;
        float var = sq * invE - mu * mu;
        sc = gg * rsqrtf(var + EPS_BN);
        sh = fmaf(-mu, sc, bb);
    };
    float scx, shx, scy, shy, scz, shz, scw, shw;
    mkss(sum4.x, sq4.x, gf.x, bf2.x, scx, shx);
    mkss(sum4.y, sq4.y, gf.y, bf2.y, scy, shy);
    mkss(sum4.z, sq4.z, gc.x, bc2.x, scz, shz);
    mkss(sum4.w, sq4.w, gc.y, bc2.y, scw, shw);

    uint2 a8 = A16[(size_t)n * 64 + l];
    const float apx = bflo(a8.x), apy = bfhi(a8.x), apz = bflo(a8.y), apw = bfhi(a8.y);
    const float sfx = -scx * LOG2E, sfy = -scy * LOG2E;
    const float bfx = -fmaf(apx, scx, shx) * LOG2E;
    const float bfy = -fmaf(apy, scy, shy) * LOG2E;
    const float sczz = scz * LOG2E, scww = scw * LOG2E;
    const float bcz = fmaf(apz, scz, shz) * LOG2E;
    const float bcw = fmaf(apw, scw, shw) * LOG2E;

    const int e0 = rowptr[n], e1 = rowptr[n + 1];
    float den0 = 0.f, num0 = 0.f, den1 = 0.f, num1 = 0.f;

    auto proc = [&](unsigned p) {
        float c0, c1, c2, c3;
        fp8quad(p, c0, c1, c2, c3);
        float ef0 = fexp2(fmaf(c0, sfx, bfx));
        float ef1 = fexp2(fmaf(c1, sfy, bfy));
        float u0  = fexp2(fmaf(c2, sczz, bcz));
        float u1  = fexp2(fmaf(c3, scww, bcw));
        float sig0 = __builtin_amdgcn_rcpf(1.f + ef0);
        float sig1 = __builtin_amdgcn_rcpf(1.f + ef1);
        float M0 = sig0 * flog2(1.f + u0);
        float M1 = sig1 * flog2(1.f + u1);
        float w0 = fexp2(t * M0);
        float w1 = fexp2(t * M1);
        den0 += w0; num0 = fmaf(M0, w0, num0);
        den1 += w1; num1 = fmaf(M1, w1, num1);
    };

    if (e1 > e0) {
        unsigned cur[4];
        int cb = min(e1 - e0, 4);
#pragma unroll
        for (int i = 0; i < 4; i++)
            if (i < cb) cur[i] = Cp8[(size_t)sidx1[e0 + i] * 64 + l];
        for (int eb = e0; eb < e1; eb += 4) {
            int nb = min(max(e1 - (eb + 4), 0), 4);
            unsigned nxt[4];
#pragma unroll
            for (int i = 0; i < 4; i++)
                if (i < nb) nxt[i] = Cp8[(size_t)sidx1[eb + 4 + i] * 64 + l];
            int pb = min(e1 - eb, 4);
#pragma unroll
            for (int i = 0; i < 4; i++)
                if (i < pb) proc(cur[i]);
#pragma unroll
            for (int i = 0; i < 4; i++) cur[i] = nxt[i];
        }
    }
    float ox = (e1 > e0) ? LN2 * num0 / den0 : 0.f;
    float oy = (e1 > e0) ? LN2 * num1 / den1 : 0.f;
    out[(size_t)n * 64 + l] = pack2bf(ox, oy);       // channels 2l, 2l+1 as bf16
}

// ---------------- BN2 stats (bf16 outbuf) ----------------
__global__ __launch_bounds__(128) void k_bn2stats(const unsigned short* __restrict__ out, float* __restrict__ sum,
                                                  float* __restrict__ sq, int N) {
    const int c = threadIdx.x;
    const int n0 = blockIdx.x * 64;
    const int nend = min(n0 + 64, N);
    float sm = 0.f, s2 = 0.f;
    for (int n = n0; n < nend; n++) {
        float v = bfu16(out[(size_t)n * 128 + c]);
        sm += v;
        s2 = fmaf(v, v, s2);
    }
    atomicAdd(&sum[c], sm);
    atomicAdd(&sq[c], s2);
}

// ---------------- fused BN2-finalize + residual+softplus + mean-pool (bf16 inputs) ----------------
template<int SPLIT>
__global__ __launch_bounds__(128) void k_h2pool(const unsigned short* __restrict__ out,
                                                const unsigned short* __restrict__ h,
                                                const int* __restrict__ gptr, const int* __restrict__ gnodes,
                                                const float* __restrict__ bn2_sum, const float* __restrict__ bn2_sq,
                                                const float* __restrict__ g2, const float* __restrict__ b2,
                                                float* __restrict__ pooled, float invN) {
    const int g = blockIdx.x & 127;
    const int sp = blockIdx.x >> 7;
    const int c = threadIdx.x;
    float mu = bn2_sum[c] * invN;
    float var = bn2_sq[c] * invN - mu * mu;
    float sc = g2[c] * rsqrtf(var + EPS_BN);
    float sh = fmaf(-mu, sc, b2[c]);
    const int i0 = gptr[g], i1 = gptr[g + 1];
    float acc = 0.f;
    for (int i = i0 + sp; i < i1; i += SPLIT) {
        int n = gnodes[i];
        float v = fmaf(bfu16(out[(size_t)n * 128 + c]), sc, sh) + bfu16(h[(size_t)n * 128 + c]);
        acc += softplus_fast(v);
    }
    if (acc != 0.f) atomicAdd(&pooled[g * 128 + c], acc);
}

// ---------------- head ----------------
__global__ __launch_bounds__(256) void k_head(const float* __restrict__ pooled, const int* __restrict__ gcount,
                                              const float* __restrict__ l1w, const float* __restrict__ l1b,
                                              const float* __restrict__ outw, const float* __restrict__ outb,
                                              float* __restrict__ dout) {
    __shared__ float p[128];
    __shared__ float red[256];
    const int g = blockIdx.x;
    const int j = threadIdx.x;
    if (j < 128) {
        float cnt = (float)max(gcount[g], 1);
        p[j] = pooled[g * 128 + j] / cnt;
    }
    __syncthreads();
    float acc = l1b[j];
    for (int k = 0; k < 128; k++) acc = fmaf(p[k], l1w[k * 256 + j], acc);
    red[j] = softplus_fast(acc) * outw[j];
    __syncthreads();
    for (int s = 128; s > 0; s >>= 1) {
        if (j < s) red[j] += red[j + s];
        __syncthreads();
    }
    if (j == 0) dout[g] = red[0] + outb[0];
}

// ---------------- launch ----------------
extern "C" void kernel_launch(void* const* d_in, const int* in_sizes, int n_in,
                              void* d_out, int out_size, void* d_ws, size_t ws_size,
                              hipStream_t stream) {
    const float* x        = (const float*)d_in[0];
    const float* hedge    = (const float*)d_in[1];
    const int*   iri      = (const int*)d_in[2];
    const int*   batch    = (const int*)d_in[3];
    const float* embed_w  = (const float*)d_in[5];
    const float* embed_b  = (const float*)d_in[6];
    const float* bembed_w = (const float*)d_in[7];
    const float* bembed_b = (const float*)d_in[8];
    const float* lin_w    = (const float*)d_in[9];
    const float* lin_b    = (const float*)d_in[10];
    const float* bn1_g    = (const float*)d_in[11];
    const float* bn1_b    = (const float*)d_in[12];
    const float* bn2_g    = (const float*)d_in[13];
    const float* bn2_b    = (const float*)d_in[14];
    const float* aggr_t   = (const float*)d_in[15];
    const float* l1_w     = (const float*)d_in[16];
    const float* l1_b     = (const float*)d_in[17];
    const float* out_w    = (const float*)d_in[18];
    const float* out_b    = (const float*)d_in[19];

    const int N   = in_sizes[0] / 92;
    const int NHE = in_sizes[1] / 40;
    const int E   = in_sizes[2] / 3;
    const int* idx0 = iri;
    const int* idx1 = iri + E;

    float* ws = (float*)d_ws;
    size_t off = 0;
    auto alloc = [&](size_t elems) -> float* {
        float* p = ws + off;
        off += (elems + 63) & ~(size_t)63;
        return p;
    };
    unsigned short* h16 = (unsigned short*)alloc((size_t)N * 64);   // N*128 bf16
    uint2* A16    = (uint2*)alloc((size_t)N * 128);                 // N*256 bf16 packed
    unsigned* Cp8 = (unsigned*)alloc((size_t)NHE * 64);             // NHE*256 fp8 packed
    unsigned short* embB  = (unsigned short*)alloc(6144);
    unsigned short* bembB = (unsigned short*)alloc(4096);
    unsigned short* waB   = (unsigned short*)alloc(16384);
    unsigned short* wcB   = (unsigned short*)alloc(16384);
    int*   rowptr = (int*)alloc((size_t)N + 1);
    int*   sidx1  = (int*)alloc((size_t)E + 8);
    int*   gptr   = (int*)alloc(129);
    int*   gnodes = (int*)alloc((size_t)N);
    unsigned* outbuf = (unsigned*)alloc((size_t)N * 64);            // N*128 bf16
    // contiguous zero region
    float* zbase  = ws + off;
    int*   hist   = (int*)alloc((size_t)N);
    int*   fill   = (int*)alloc((size_t)N);
    int*   gfill  = (int*)alloc(128);
    float* bn1_sum = alloc(256);
    float* bn1_sq  = alloc(256);
    float* bn2_sum = alloc(128);
    float* bn2_sq  = alloc(128);
    float* pooled  = alloc(128 * 128);
    int*   gcount  = (int*)alloc(128);
    size_t zbytes = (size_t)((ws + off) - zbase) * sizeof(float);
    (void)ws_size;  // ~77MB; fit verified

    hipMemsetAsync(zbase, 0, zbytes, stream);

    // frag-major bf16 weight prep + fused MFMA GEMM chains
    k_prepw<<<320, 256, 0, stream>>>(embed_w, bembed_w, lin_w, embB, bembB, waB, wcB);
    const int mtN   = (N + 31) / 32;
    const int mtNHE = (NHE + 31) / 32;
    mfma_fused<92, 3, 1><<<mtN, 256, 0, stream>>>(x, embB, embed_b, waB, lin_b, h16, A16, N);
    mfma_fused<40, 2, 2><<<mtNHE, 256, 0, stream>>>(hedge, bembB, bembed_b, wcB, nullptr, nullptr, Cp8, NHE);

    // CSR build
    k_hist2<<<(E + 255) / 256, 256, 0, stream>>>(idx0, batch, hist, gcount, E, N);
    k_scanall<<<1, 1024, 0, stream>>>(hist, rowptr, gcount, gptr, N);
    k_scatter2<<<(E + 255) / 256, 256, 0, stream>>>(idx0, idx1, batch, rowptr, gptr,
                                                    fill, gfill, sidx1, gnodes, E, N);

    // BN1 stats (rowptr-derived node runs)
    const int STATS_BLOCKS = 2048;
    int per_slot = ((E + STATS_BLOCKS * 4 - 1) / (STATS_BLOCKS * 4) + 7) & ~7;
    k_stats<<<STATS_BLOCKS, 256, 0, stream>>>(A16, Cp8, rowptr, sidx1, bn1_sum, bn1_sq, E, N, per_slot);

    // fused BN1-finalize + message + softmax aggregation
    k_aggr<<<(N + 3) / 4, 256, 0, stream>>>(A16, Cp8, rowptr, sidx1, bn1_sum, bn1_sq,
                                            bn1_g, bn1_b, aggr_t, outbuf, 1.0f / (float)E, N);

    // BN2 stats + fused finalize/residual/softplus/pool
    k_bn2stats<<<(N + 63) / 64, 128, 0, stream>>>((const unsigned short*)outbuf, bn2_sum, bn2_sq, N);
    k_h2pool<16><<<128 * 16, 128, 0, stream>>>((const unsigned short*)outbuf, h16, gptr, gnodes,
                                               bn2_sum, bn2_sq, bn2_g, bn2_b, pooled, 1.0f / (float)N);

    // head
    k_head<<<128, 256, 0, stream>>>(pooled, gcount, l1_w, l1_b, out_w, out_b, (float*)d_out);
}